// Round 13
// baseline (322.361 us; speedup 1.0000x reference)
//
#include <hip/hip_runtime.h>
#include <hip/hip_bf16.h>

#define BB 8
#define LL 512
#define CC 8
#define NITER 3
#define NP 8  // split-K parts for mm_fz

typedef __attribute__((ext_vector_type(8))) short bf16x8;
typedef __attribute__((ext_vector_type(4))) float f32x4;
typedef unsigned short u16;

#define MFMA(A, B, C) __builtin_amdgcn_mfma_f32_16x16x32_bf16(A, B, C, 0, 0, 0)

__device__ inline u16 f2b(float f) {
  __hip_bfloat16 h = __float2bfloat16(f);
  return *reinterpret_cast<u16*>(&h);
}
__device__ inline float b2f(u16 u) {
  __hip_bfloat16 h;
  *reinterpret_cast<u16*>(&h) = u;
  return __bfloat162float(h);
}
__device__ inline void split2(float v, u16& hi, u16& lo) {
  hi = f2b(v);
  lo = f2b(v - b2f(hi));
}

// Stage a [64][64] bf16 tile (row stride ld) into LDS, XOR-swizzled.
__device__ inline void stageT(u16* lds, const u16* __restrict__ src, int ld,
                              int t, int nthr) {
  for (int ch = t; ch < 512; ch += nthr) {
    int r = ch >> 3, seg = ch & 7;
    int byte = (r * 128 + seg * 16) ^ ((r & 7) << 4);
    *(bf16x8*)((char*)lds + byte) = *(const bf16x8*)(src + r * ld + seg * 8);
  }
}
// mfma_16x16x32 operand fragment from swizzled tile: rows row0..row0+15.
__device__ inline bf16x8 frag64(const u16* lds, int row0, int ks, int lane) {
  int r = row0 + (lane & 15);
  int byte = (r * 128 + ks * 64 + ((lane >> 4) << 4)) ^ ((r & 7) << 4);
  return *(const bf16x8*)((const char*)lds + byte);
}
// split-precision accumulate: acc += Ah*Bh + Ah*Bl + Al*Bh
__device__ inline void mfma3(f32x4& acc, bf16x8 ah, bf16x8 al, bf16x8 bh,
                             bf16x8 bl) {
  acc = MFMA(ah, bh, acc);
  acc = MFMA(ah, bl, acc);
  acc = MFMA(al, bh, acc);
}

#define ACC_INIT {{0.f,0.f,0.f,0.f},{0.f,0.f,0.f,0.f},{0.f,0.f,0.f,0.f},{0.f,0.f,0.f,0.f}}

// ---------------------------------------------------------------------------
// repack ternary to split pairs: TB[k,c][e][a], T1p[a][k,c,e], T2p[e][k,c,a]
// ---------------------------------------------------------------------------
__global__ __launch_bounds__(256) void repack_kernel(
    const float* __restrict__ T, u16* TBh, u16* TBl, u16* T1h, u16* T1l,
    u16* T2h, u16* T2l) {
  int tid = blockIdx.x * 256 + threadIdx.x;  // [2][64][64][8]
  int c = tid & 7, e = (tid >> 3) & 63, a = (tid >> 9) & 63, kk = tid >> 15;
  u16 hi, lo;
  split2(T[tid], hi, lo);
  int iTB = ((kk * 8 + c) * 64 + e) * 64 + a;
  int i1 = a * 1024 + kk * 512 + c * 64 + e;
  int i2 = e * 1024 + kk * 512 + c * 64 + a;
  TBh[iTB] = hi; TBl[iTB] = lo;
  T1h[i1] = hi;  T1l[i1] = lo;
  T2h[i2] = hi;  T2l[i2] = lo;
}

// ---------------------------------------------------------------------------
// q_z = softmax(x) * m1 ; fp32 + split-bf16 copies  (iteration 0 only)
// ---------------------------------------------------------------------------
__global__ __launch_bounds__(64) void softmax_z_kernel(
    const float* __restrict__ in, const int* __restrict__ mask,
    float* __restrict__ qz, u16* __restrict__ qzh, u16* __restrict__ qzl) {
  int row = blockIdx.x;
  int t = threadIdx.x;
  float v = in[row * 64 + t];
  float m = v;
  for (int o = 32; o; o >>= 1) m = fmaxf(m, __shfl_xor(m, o));
  float e = __expf(v - m);
  float s = e;
  for (int o = 32; o; o >>= 1) s += __shfl_xor(s, o);
  float mi = (mask[row] != 0) ? 1.f : 0.f;
  float r = e / s * mi;
  qz[row * 64 + t] = r;
  u16 hi, lo;
  split2(r, hi, lo);
  qzh[row * 64 + t] = hi;
  qzl[row * 64 + t] = lo;
}

// ---------------------------------------------------------------------------
// fused: blk<1024 -> t1[kk,b,c][i][e] = sum_a qz[b,i,a]*T[kk,a,e,c]
//        blk>=1024 -> qzT[b][a][i] = qz[b][i][a]  (hi and lo)
// ---------------------------------------------------------------------------
__global__ __launch_bounds__(256) void t1qzT_kernel(
    const u16* __restrict__ qzh, const u16* __restrict__ qzl,
    const u16* __restrict__ TBh, const u16* __restrict__ TBl,
    u16* __restrict__ t1h, u16* __restrict__ t1l, u16* __restrict__ qzTh,
    u16* __restrict__ qzTl) {
  __shared__ u16 smem[16384];  // 32 KB, aliased by both paths
  int blk = blockIdx.x;
  int t = threadIdx.x;
  if (blk >= 1024) {
    int blk2 = blk - 1024;  // sel*64 + b*8 + it
    int it = blk2 & 7, b = (blk2 >> 3) & 7, sel = blk2 >> 6;
    const u16* src = sel ? qzl : qzh;
    u16* dst = sel ? qzTl : qzTh;
    u16(*s)[65] = (u16(*)[65])smem;
    for (int p = t; p < 4096; p += 256) {
      int r = p >> 6, a = p & 63;
      s[r][a] = src[(b * 512 + it * 64 + r) * 64 + a];
    }
    __syncthreads();
    for (int p = t; p < 4096; p += 256) {
      int a = p >> 6, i = p & 63;
      dst[(b * 64 + a) * 512 + it * 64 + i] = s[i][a];
    }
    return;
  }
  int it = blk & 7, c = (blk >> 3) & 7, b = (blk >> 6) & 7, kk = blk >> 9;
  u16* ah_s = smem;
  u16* al_s = smem + 4096;
  u16* bh_s = smem + 8192;
  u16* bl_s = smem + 12288;
  int lane = t & 63, w = t >> 6;
  stageT(ah_s, qzh + (b * 512 + it * 64) * 64, 64, t, 256);
  stageT(al_s, qzl + (b * 512 + it * 64) * 64, 64, t, 256);
  stageT(bh_s, TBh + (kk * 8 + c) * 4096, 64, t, 256);
  stageT(bl_s, TBl + (kk * 8 + c) * 4096, 64, t, 256);
  __syncthreads();
  f32x4 acc[4] = ACC_INIT;
  for (int ks = 0; ks < 2; ks++) {
    bf16x8 ah = frag64(ah_s, w * 16, ks, lane);
    bf16x8 al = frag64(al_s, w * 16, ks, lane);
#pragma unroll
    for (int nt = 0; nt < 4; nt++)
      mfma3(acc[nt], ah, al, frag64(bh_s, nt * 16, ks, lane),
            frag64(bl_s, nt * 16, ks, lane));
  }
  size_t base = ((size_t)((kk * 8 + b) * 8 + c)) * 32768;
  int rb = (lane >> 4) * 4, cl = lane & 15;
#pragma unroll
  for (int nt = 0; nt < 4; nt++)
#pragma unroll
    for (int r = 0; r < 4; r++) {
      size_t o = base + (size_t)(it * 64 + w * 16 + rb + r) * 64 + nt * 16 + cl;
      u16 h, l;
      split2(acc[nt][r], h, l);
      t1h[o] = h;
      t1l[o] = l;
    }
}

// ---------------------------------------------------------------------------
// a1: fused no-max softmax + A1 = (qh*dm) @ qz, paired-tile passes (2 j-tiles
// per barrier window).  GEMM2 B-operand hi-only.  Writes sts.
// ---------------------------------------------------------------------------
#define A1_G1(BX0, BX1, JTv, TFH, TFL, KKis0, QH)                            \
  {                                                                          \
    f32x4 accq0 = {0.f, 0.f, 0.f, 0.f}, accq1 = {0.f, 0.f, 0.f, 0.f};       \
    _Pragma("unroll") for (int ks = 0; ks < 2; ks++) {                       \
      bf16x8 bh0 = frag64(BX0, (nh * 2) * 16, ks, lane);                     \
      bf16x8 bl0 = frag64(BX1, (nh * 2) * 16, ks, lane);                     \
      bf16x8 bh1 = frag64(BX0, (nh * 2 + 1) * 16, ks, lane);                 \
      bf16x8 bl1 = frag64(BX1, (nh * 2 + 1) * 16, ks, lane);                 \
      accq0 = MFMA(TFH[ks], bh0, accq0);                                     \
      accq0 = MFMA(TFH[ks], bl0, accq0);                                     \
      accq0 = MFMA(TFL[ks], bh0, accq0);                                     \
      accq1 = MFMA(TFH[ks], bh1, accq1);                                     \
      accq1 = MFMA(TFH[ks], bl1, accq1);                                     \
      accq1 = MFMA(TFL[ks], bh1, accq1);                                     \
    }                                                                        \
    _Pragma("unroll") for (int ntl = 0; ntl < 2; ntl++) {                    \
      int col = (nh * 2 + ntl) * 16 + cl;                                    \
      int jg = (JTv) * 64 + col;                                             \
      float mj = (mask[b * 512 + jg] != 0) ? 1.f : 0.f;                      \
      _Pragma("unroll") for (int r = 0; r < 4; r++) {                        \
        int row = rg * 16 + g * 4 + r;                                       \
        int ig = it * 64 + row;                                              \
        float e = __expf(ntl ? accq1[r] : accq0[r]);                         \
        float es, q;                                                         \
        if (KKis0) {                                                         \
          es = (jg > ig) ? e : ((jg == ig) ? 1.f : 0.f);                     \
          q = (jg > ig) ? e * mj : 0.f;                                      \
        } else {                                                             \
          es = (jg < ig) ? e : 0.f;                                          \
          q = (jg < ig) ? e * mj : 0.f;                                      \
        }                                                                    \
        s_run[r] += es;                                                      \
        int byte = (row * 128 + col * 2) ^ ((row & 7) << 4);                 \
        *(u16*)((char*)(QH) + byte) = f2b(q);                                \
      }                                                                      \
    }                                                                        \
  }

#define A1_G2(QH, BT, ACC)                                                   \
  _Pragma("unroll") for (int ks = 0; ks < 2; ks++) {                         \
    bf16x8 ah = frag64(QH, rg * 16, ks, lane);                               \
    _Pragma("unroll") for (int ntl = 0; ntl < 2; ntl++) {                    \
      bf16x8 bh = frag64(BT, (nh * 2 + ntl) * 16, ks, lane);                 \
      ACC[ntl] = MFMA(ah, bh, ACC[ntl]);                                     \
    }                                                                        \
  }

__global__ __launch_bounds__(512, 4) void a1_kernel(
    const u16* __restrict__ t1h, const u16* __restrict__ t1l,
    const u16* __restrict__ qzh, const u16* __restrict__ qzl,
    const u16* __restrict__ qzTh, const int* __restrict__ mask,
    float* __restrict__ sts, u16* __restrict__ A1h, u16* __restrict__ A1l) {
  int blk = blockIdx.x;  // b*64 + c*8 + it
  int it = blk & 7, c = (blk >> 3) & 7, b = blk >> 6;
  __shared__ u16 smem[33024];  // 66048 B
  u16* bx0a = smem;
  u16* bx1a = smem + 4096;
  u16* bt0a = smem + 8192;
  u16* bx0b = smem + 12288;
  u16* bx1b = smem + 16384;
  u16* bt0b = smem + 20480;
  u16* qhA = smem + 24576;
  u16* qhB = smem + 28672;
  float* ps = (float*)(smem + 32768);  // [2][64]
  int t = threadIdx.x, lane = t & 63, w = t >> 6, cl = lane & 15, g = lane >> 4;
  int rg = w & 3, nh = w >> 2;
  const size_t KSTR = (size_t)64 * 32768;
  size_t tb = ((size_t)(b * 8 + c)) * 32768 + it * 4096;
  // prologue: stage both t1 tiles (via temp buffers), hoist A-frags to regs
  stageT(bx0a, t1h + tb, 64, t, 512);
  stageT(bx1a, t1l + tb, 64, t, 512);
  stageT(bt0a, t1h + tb + KSTR, 64, t, 512);
  stageT(bx0b, t1l + tb + KSTR, 64, t, 512);
  __syncthreads();
  bf16x8 tf0h[2], tf0l[2], tf1h[2], tf1l[2];
#pragma unroll
  for (int ks = 0; ks < 2; ks++) {
    tf0h[ks] = frag64(bx0a, rg * 16, ks, lane);
    tf0l[ks] = frag64(bx1a, rg * 16, ks, lane);
    tf1h[ks] = frag64(bt0a, rg * 16, ks, lane);
    tf1l[ks] = frag64(bx0b, rg * 16, ks, lane);
  }
  float mi_[4], s_run[4];
#pragma unroll
  for (int r = 0; r < 4; r++) {
    mi_[r] = (mask[b * 512 + it * 64 + rg * 16 + g * 4 + r] != 0) ? 1.f : 0.f;
    s_run[r] = 0.f;
  }
  f32x4 accU[2] = {{0.f, 0.f, 0.f, 0.f}, {0.f, 0.f, 0.f, 0.f}};
  f32x4 accL[2] = {{0.f, 0.f, 0.f, 0.f}, {0.f, 0.f, 0.f, 0.f}};

#pragma unroll 1
  for (int p = 0; p < 4; p++) {
    int jta = 2 * p, jtb = 2 * p + 1;
    __syncthreads();  // prior GEMM2 reads / hoist reads done
    stageT(bx0a, qzh + (b * 512 + jta * 64) * 64, 64, t, 512);
    stageT(bx1a, qzl + (b * 512 + jta * 64) * 64, 64, t, 512);
    stageT(bt0a, qzTh + (size_t)b * 32768 + jta * 64, 512, t, 512);
    stageT(bx0b, qzh + (b * 512 + jtb * 64) * 64, 64, t, 512);
    stageT(bx1b, qzl + (b * 512 + jtb * 64) * 64, 64, t, 512);
    stageT(bt0b, qzTh + (size_t)b * 32768 + jtb * 64, 512, t, 512);
    __syncthreads();
    if (jta > it) {  // both tiles above diagonal
      A1_G1(bx0a, bx1a, jta, tf0h, tf0l, true, qhA)
      A1_G1(bx0b, bx1b, jtb, tf0h, tf0l, true, qhB)
      __syncthreads();
      A1_G2(qhA, bt0a, accU)
      A1_G2(qhB, bt0b, accU)
    } else if (jtb < it) {  // both below
      A1_G1(bx0a, bx1a, jta, tf1h, tf1l, false, qhA)
      A1_G1(bx0b, bx1b, jtb, tf1h, tf1l, false, qhB)
      __syncthreads();
      A1_G2(qhA, bt0a, accL)
      A1_G2(qhB, bt0b, accL)
    } else if (jta == it) {  // diag at a, b above
      A1_G1(bx0a, bx1a, jta, tf0h, tf0l, true, qhA)
      A1_G1(bx0b, bx1b, jtb, tf0h, tf0l, true, qhB)
      __syncthreads();
      A1_G2(qhA, bt0a, accU)
      A1_G2(qhB, bt0b, accU)
      __syncthreads();  // qhA reuse
      A1_G1(bx0a, bx1a, jta, tf1h, tf1l, false, qhA)
      __syncthreads();
      A1_G2(qhA, bt0a, accL)
    } else {  // jtb == it: a below, diag at b
      A1_G1(bx0a, bx1a, jta, tf1h, tf1l, false, qhA)
      A1_G1(bx0b, bx1b, jtb, tf0h, tf0l, true, qhB)
      __syncthreads();
      A1_G2(qhA, bt0a, accL)
      A1_G2(qhB, bt0b, accU)
      __syncthreads();  // qhB reuse
      A1_G1(bx0b, bx1b, jtb, tf1h, tf1l, false, qhB)
      __syncthreads();
      A1_G2(qhB, bt0b, accL)
    }
  }
  // epilogue: one reduction for s, then scale + store
#pragma unroll
  for (int r = 0; r < 4; r++) {
    float s = s_run[r];
    s += __shfl_xor(s, 1);
    s += __shfl_xor(s, 2);
    s += __shfl_xor(s, 4);
    s += __shfl_xor(s, 8);
    s_run[r] = s;
  }
  __syncthreads();
  if (cl == 0) {
#pragma unroll
    for (int r = 0; r < 4; r++) ps[nh * 64 + rg * 16 + g * 4 + r] = s_run[r];
  }
  __syncthreads();
#pragma unroll
  for (int r = 0; r < 4; r++) {
    int row = rg * 16 + g * 4 + r;
    float stot = ps[row] + ps[64 + row];
    float scale = mi_[r] / stot;
    int grow = it * 64 + row;
#pragma unroll
    for (int ntl = 0; ntl < 2; ntl++) {
      size_t o0 = ((size_t)b * 512 + grow) * 1024 + c * 64 +
                  (nh * 2 + ntl) * 16 + cl;
      u16 h, l;
      split2(accU[ntl][r] * scale, h, l);
      A1h[o0] = h;
      A1l[o0] = l;
      split2(accL[ntl][r] * scale, h, l);
      A1h[o0 + 512] = h;
      A1l[o0 + 512] = l;
    }
    if (nh == 0 && cl == 0) sts[(b * 8 + c) * 512 + grow] = stot;
  }
}

// ---------------------------------------------------------------------------
// a2: A2[b][j][kk,c,a] = sum_i qh[kk][i][j]·qz[i][a], paired-tile passes.
// ---------------------------------------------------------------------------
#define A2_G1(TSX0, TSX1, IIv, KKis0, QH, SIMI)                              \
  {                                                                          \
    f32x4 accq0 = {0.f, 0.f, 0.f, 0.f}, accq1 = {0.f, 0.f, 0.f, 0.f};       \
    _Pragma("unroll") for (int ks = 0; ks < 2; ks++) {                       \
      bf16x8 bh0 = frag64(TSX0, (nh * 2) * 16, ks, lane);                    \
      bf16x8 bl0 = frag64(TSX1, (nh * 2) * 16, ks, lane);                    \
      bf16x8 bh1 = frag64(TSX0, (nh * 2 + 1) * 16, ks, lane);                \
      bf16x8 bl1 = frag64(TSX1, (nh * 2 + 1) * 16, ks, lane);                \
      accq0 = MFMA(afh[ks], bh0, accq0);                                     \
      accq0 = MFMA(afh[ks], bl0, accq0);                                     \
      accq0 = MFMA(afl[ks], bh0, accq0);                                     \
      accq1 = MFMA(afh[ks], bh1, accq1);                                     \
      accq1 = MFMA(afh[ks], bl1, accq1);                                     \
      accq1 = MFMA(afl[ks], bh1, accq1);                                     \
    }                                                                        \
    _Pragma("unroll") for (int ntl = 0; ntl < 2; ntl++) {                    \
      int col = (nh * 2 + ntl) * 16 + cl;                                    \
      int ig = (IIv) * 64 + col;                                             \
      float sim = (SIMI)[col];                                               \
      _Pragma("unroll") for (int r = 0; r < 4; r++) {                        \
        int row = rg * 16 + g * 4 + r;                                       \
        int jg = jt * 64 + row;                                              \
        float e = __expf(ntl ? accq1[r] : accq0[r]);                         \
        bool keep = KKis0 ? (jg > ig) : (jg < ig);                           \
        float q = keep ? e * sim * mjrow[r] : 0.f;                           \
        int byte = (row * 128 + col * 2) ^ ((row & 7) << 4);                 \
        *(u16*)((char*)(QH) + byte) = f2b(q);                                \
      }                                                                      \
    }                                                                        \
  }

__global__ __launch_bounds__(512, 4) void a2_kernel(
    const u16* __restrict__ t1h, const u16* __restrict__ t1l,
    const u16* __restrict__ qzh, const u16* __restrict__ qzl,
    const u16* __restrict__ qzTh, const float* __restrict__ sts,
    const int* __restrict__ mask, u16* __restrict__ A2h,
    u16* __restrict__ A2l) {
  int blk = blockIdx.x;  // b*64 + c*8 + jt
  int jt = blk & 7, c = (blk >> 3) & 7, b = blk >> 6;
  __shared__ u16 smem[33024];  // 66048 B
  u16* tsx0a = smem;
  u16* tsx1a = smem + 4096;
  u16* bt0a = smem + 8192;
  u16* tsx0b = smem + 12288;
  u16* tsx1b = smem + 16384;
  u16* bt0b = smem + 20480;
  u16* qhA = smem + 24576;
  u16* qhB = smem + 28672;
  float* simiA = (float*)(smem + 32768);  // [64]
  float* simiB = simiA + 64;              // [64]
  int t = threadIdx.x, lane = t & 63, w = t >> 6, cl = lane & 15, g = lane >> 4;
  int rg = w & 3, nh = w >> 2;
  const size_t KSTR = (size_t)64 * 32768;
  size_t tbb = ((size_t)(b * 8 + c)) * 32768;
  // prologue: stage qz[jt] (temp), hoist A-frags
  stageT(tsx0a, qzh + (b * 512 + jt * 64) * 64, 64, t, 512);
  stageT(tsx1a, qzl + (b * 512 + jt * 64) * 64, 64, t, 512);
  __syncthreads();
  bf16x8 afh[2], afl[2];
#pragma unroll
  for (int ks = 0; ks < 2; ks++) {
    afh[ks] = frag64(tsx0a, rg * 16, ks, lane);
    afl[ks] = frag64(tsx1a, rg * 16, ks, lane);
  }
  float mjrow[4];
#pragma unroll
  for (int r = 0; r < 4; r++) {
    int jg = jt * 64 + rg * 16 + g * 4 + r;
    mjrow[r] = (mask[b * 512 + jg] != 0) ? 1.f : 0.f;
  }
  f32x4 accU[2] = {{0.f, 0.f, 0.f, 0.f}, {0.f, 0.f, 0.f, 0.f}};
  f32x4 accL[2] = {{0.f, 0.f, 0.f, 0.f}, {0.f, 0.f, 0.f, 0.f}};

#pragma unroll 1
  for (int p = 0; p < 4; p++) {
    int iia = 2 * p, iib = 2 * p + 1;
    __syncthreads();  // prior GEMM2 reads / hoist reads done
    size_t tsa = tbb + iia * 4096 + ((iia <= jt) ? 0 : KSTR);
    size_t tsb = tbb + iib * 4096 + ((iib <= jt) ? 0 : KSTR);
    stageT(tsx0a, t1h + tsa, 64, t, 512);
    stageT(tsx1a, t1l + tsa, 64, t, 512);
    stageT(bt0a, qzTh + (size_t)b * 32768 + iia * 64, 512, t, 512);
    stageT(tsx0b, t1h + tsb, 64, t, 512);
    stageT(tsx1b, t1l + tsb, 64, t, 512);
    stageT(bt0b, qzTh + (size_t)b * 32768 + iib * 64, 512, t, 512);
    if (t < 64) {
      int igA = iia * 64 + t, igB = iib * 64 + t;
      simiA[t] =
          ((mask[b * 512 + igA] != 0) ? 1.f : 0.f) / sts[(b * 8 + c) * 512 + igA];
      simiB[t] =
          ((mask[b * 512 + igB] != 0) ? 1.f : 0.f) / sts[(b * 8 + c) * 512 + igB];
    }
    __syncthreads();
    if (iib < jt) {  // both i < j
      A2_G1(tsx0a, tsx1a, iia, true, qhA, simiA)
      A2_G1(tsx0b, tsx1b, iib, true, qhB, simiB)
      __syncthreads();
      A1_G2(qhA, bt0a, accU)
      A1_G2(qhB, bt0b, accU)
    } else if (iia > jt) {  // both i > j
      A2_G1(tsx0a, tsx1a, iia, false, qhA, simiA)
      A2_G1(tsx0b, tsx1b, iib, false, qhB, simiB)
      __syncthreads();
      A1_G2(qhA, bt0a, accL)
      A1_G2(qhB, bt0b, accL)
    } else if (iia == jt) {  // diag at a; b: i > j
      A2_G1(tsx0a, tsx1a, iia, true, qhA, simiA)
      A2_G1(tsx0b, tsx1b, iib, false, qhB, simiB)
      __syncthreads();  // GEMM1 reads of tsx_a done -> safe to restage
      stageT(tsx0a, t1h + tbb + iia * 4096 + KSTR, 64, t, 512);
      stageT(tsx1a, t1l + tbb + iia * 4096 + KSTR, 64, t, 512);
      A1_G2(qhA, bt0a, accU)
      A1_G2(qhB, bt0b, accL)
      __syncthreads();  // restaged tsx_a visible; qhA reads done
      A2_G1(tsx0a, tsx1a, iia, false, qhA, simiA)
      __syncthreads();
      A1_G2(qhA, bt0a, accL)
    } else {  // iib == jt: a: i < j; diag at b
      A2_G1(tsx0a, tsx1a, iia, true, qhA, simiA)
      A2_G1(tsx0b, tsx1b, iib, true, qhB, simiB)
      __syncthreads();
      stageT(tsx0b, t1h + tbb + iib * 4096 + KSTR, 64, t, 512);
      stageT(tsx1b, t1l + tbb + iib * 4096 + KSTR, 64, t, 512);
      A1_G2(qhA, bt0a, accU)
      A1_G2(qhB, bt0b, accU)
      __syncthreads();
      A2_G1(tsx0b, tsx1b, iib, false, qhB, simiB)
      __syncthreads();
      A1_G2(qhB, bt0b, accL)
    }
  }
#pragma unroll
  for (int r = 0; r < 4; r++) {
    int row = jt * 64 + rg * 16 + g * 4 + r;
#pragma unroll
    for (int ntl = 0; ntl < 2; ntl++) {
      size_t o0 = ((size_t)b * 512 + row) * 1024 + c * 64 +
                  (nh * 2 + ntl) * 16 + cl;
      u16 h, l;
      split2(accU[ntl][r], h, l);
      A2h[o0] = h;
      A2l[o0] = l;
      split2(accL[ntl][r], h, l);
      A2h[o0 + 512] = h;
      A2l[o0 + 512] = l;
    }
  }
}

// ---------------------------------------------------------------------------
// F{1,2} partials: Fp[part][b][m][n] = sum_{K part} A[b][m][K]·Tp[n][K]
// blk = sel*512 + part*64 + b*8 + it  (sel: 0->F1, 1->F2)
// ---------------------------------------------------------------------------
__global__ __launch_bounds__(256) void mm_fz_kernel(
    const u16* __restrict__ A1h, const u16* __restrict__ A1l,
    const u16* __restrict__ A2h, const u16* __restrict__ A2l,
    const u16* __restrict__ T1ph, const u16* __restrict__ T1pl,
    const u16* __restrict__ T2ph, const u16* __restrict__ T2pl,
    float* __restrict__ F1p, float* __restrict__ F2p) {
  int blk = blockIdx.x;
  int it = blk & 7, b = (blk >> 3) & 7, part = (blk >> 6) & 7, sel = blk >> 9;
  const u16* Ah = sel ? A2h : A1h;
  const u16* Al = sel ? A2l : A1l;
  const u16* Bh = sel ? T2ph : T1ph;
  const u16* Bl = sel ? T2pl : T1pl;
  float* Fp = (sel ? F2p : F1p) + (size_t)part * (BB * 512 * 64);
  __shared__ u16 ah_s[4096], al_s[4096], bh_s[4096], bl_s[4096];
  int t = threadIdx.x, lane = t & 63, w = t >> 6;
  f32x4 acc[4] = ACC_INIT;
  size_t abase = ((size_t)b * 512 + it * 64) * 1024;
  for (int cc2 = 0; cc2 < 2; cc2++) {
    int ch = part * 2 + cc2;
    __syncthreads();
    stageT(ah_s, Ah + abase + ch * 64, 1024, t, 256);
    stageT(al_s, Al + abase + ch * 64, 1024, t, 256);
    stageT(bh_s, Bh + ch * 64, 1024, t, 256);
    stageT(bl_s, Bl + ch * 64, 1024, t, 256);
    __syncthreads();
    for (int ks = 0; ks < 2; ks++) {
      bf16x8 ah = frag64(ah_s, w * 16, ks, lane);
      bf16x8 al = frag64(al_s, w * 16, ks, lane);
#pragma unroll
      for (int nt = 0; nt < 4; nt++)
        mfma3(acc[nt], ah, al, frag64(bh_s, nt * 16, ks, lane),
              frag64(bl_s, nt * 16, ks, lane));
    }
  }
  int rb = (lane >> 4) * 4, cl = lane & 15;
#pragma unroll
  for (int nt = 0; nt < 4; nt++)
#pragma unroll
    for (int r = 0; r < 4; r++)
      Fp[((size_t)b * 512 + it * 64 + w * 16 + rb + r) * 64 + nt * 16 + cl] =
          acc[nt][r];
}

// ---------------------------------------------------------------------------
// fused q_g + F_Z (+ Z-softmax for non-final iters)
// ---------------------------------------------------------------------------
__global__ __launch_bounds__(256) void fzqg_kernel(
    const float* __restrict__ x, const float* __restrict__ F1p,
    const float* __restrict__ F2p, float* __restrict__ qz,
    u16* __restrict__ qzh, u16* __restrict__ qzl, const float* __restrict__ gw,
    const int* __restrict__ mask, float* __restrict__ out, int final_) {
  int blk = blockIdx.x;
  int ic = blk & 15, b = blk >> 4;
  int i0 = ic * 32;
  int t = threadIdx.x;
  __shared__ float gw_s[64][65];
  __shared__ float qz_s[32][64];
  __shared__ float fg_s[32][65];
  for (int p = t; p < 4096; p += 256) gw_s[p >> 6][p & 63] = gw[p];
  for (int p = t; p < 2048; p += 256) {
    int il = p >> 6, a = p & 63;
    qz_s[il][a] = qz[(b * LL + i0 + il) * 64 + a];
  }
  __syncthreads();
  int gcol = t & 63, il0 = t >> 6;
#pragma unroll
  for (int s = 0; s < 8; s++) {
    int il = il0 + 4 * s;
    float acc = 0.f;
    for (int a = 0; a < 64; a++) acc += qz_s[il][a] * gw_s[gcol][a];
    fg_s[il][gcol] = acc;
  }
  __syncthreads();
  {
    int r = t >> 3, k = t & 7;
    float v[8];
#pragma unroll
    for (int u = 0; u < 8; u++) v[u] = fg_s[r][k * 8 + u];
    float m = v[0];
#pragma unroll
    for (int u = 1; u < 8; u++) m = fmaxf(m, v[u]);
    for (int o = 1; o < 8; o <<= 1) m = fmaxf(m, __shfl_xor(m, o));
    float s = 0.f;
#pragma unroll
    for (int u = 0; u < 8; u++) s += __expf(v[u] - m);
    for (int o = 1; o < 8; o <<= 1) s += __shfl_xor(s, o);
    float mi = (mask[b * LL + i0 + r] != 0) ? 1.f : 0.f;
    float inv = mi / s;
#pragma unroll
    for (int u = 0; u < 8; u++) fg_s[r][k * 8 + u] = __expf(v[u] - m) * inv;
  }
  __syncthreads();
  int a = t & 63;
#pragma unroll
  for (int s = 0; s < 8; s++) {
    int il = il0 + 4 * s;
    float acc = 0.f;
    for (int g2 = 0; g2 < 64; g2++) acc += fg_s[il][g2] * gw_s[g2][a];
    size_t idx = (size_t)(b * LL + i0 + il) * 64 + a;
    float fs = x[idx] + acc;
    for (int p = 0; p < NP; p++)
      fs += F1p[(size_t)p * (BB * 512 * 64) + idx] +
            F2p[(size_t)p * (BB * 512 * 64) + idx];
    if (final_) {
      out[idx] = fs;
    } else {
      float m = fs;
      for (int o = 32; o; o >>= 1) m = fmaxf(m, __shfl_xor(m, o));
      float e = __expf(fs - m);
      float ss = e;
      for (int o = 32; o; o >>= 1) ss += __shfl_xor(ss, o);
      float mi = (mask[b * LL + i0 + il] != 0) ? 1.f : 0.f;
      float r = e / ss * mi;
      qz[idx] = r;
      u16 hi, lo;
      split2(r, hi, lo);
      qzh[idx] = hi;
      qzl[idx] = lo;
    }
  }
}

// ---------------------------------------------------------------------------
extern "C" void kernel_launch(void* const* d_in, const int* in_sizes, int n_in,
                              void* d_out, int out_size, void* d_ws,
                              size_t ws_size, hipStream_t stream) {
  const float* x = (const float*)d_in[0];
  const int* mask = (const int*)d_in[1];
  const float* ternary = (const float*)d_in[2];
  const float* gw = (const float*)d_in[3];
  float* out = (float*)d_out;

  char* w = (char*)d_ws;
  float* qz_f = (float*)(w);                           // 1 MB
  u16* qzh = (u16*)(w + (2 << 20));                    // 512 KB
  u16* qzl = (u16*)(w + (2 << 20) + (512 << 10));      // 512 KB
  u16* qzTh = (u16*)(w + (3 << 20));                   // 512 KB
  u16* qzTl = (u16*)(w + (3 << 20) + (512 << 10));     // 512 KB
  u16* TBh = (u16*)(w + (4 << 20));                    // 6 x 128 KB
  u16* TBl = (u16*)(w + (4 << 20) + (128 << 10));
  u16* T1ph = (u16*)(w + (4 << 20) + (256 << 10));
  u16* T1pl = (u16*)(w + (4 << 20) + (384 << 10));
  u16* T2ph = (u16*)(w + (4 << 20) + (512 << 10));
  u16* T2pl = (u16*)(w + (4 << 20) + (640 << 10));
  float* sts = (float*)(w + (5 << 20));                // 128 KB
  float* F1p = (float*)(w + (6 << 20));                // 8 MB
  float* F2p = (float*)(w + (14 << 20));               // 8 MB
  u16* t1h = (u16*)(w + (22 << 20));                   // 8 MB
  u16* t1l = (u16*)(w + (30 << 20));                   // 8 MB
  u16* A1h = (u16*)(w + (38 << 20));                   // 8 MB
  u16* A1l = (u16*)(w + (46 << 20));                   // 8 MB
  u16* A2h = (u16*)(w + (54 << 20));                   // 8 MB
  u16* A2l = (u16*)(w + (62 << 20));                   // 8 MB -> 70 MB total

  repack_kernel<<<256, 256, 0, stream>>>(ternary, TBh, TBl, T1ph, T1pl, T2ph,
                                         T2pl);
  softmax_z_kernel<<<BB * LL, 64, 0, stream>>>(x, mask, qz_f, qzh, qzl);
  for (int iter = 0; iter < NITER; iter++) {
    t1qzT_kernel<<<1152, 256, 0, stream>>>(qzh, qzl, TBh, TBl, t1h, t1l, qzTh,
                                           qzTl);
    a1_kernel<<<512, 512, 0, stream>>>(t1h, t1l, qzh, qzl, qzTh, mask, sts,
                                       A1h, A1l);
    a2_kernel<<<512, 512, 0, stream>>>(t1h, t1l, qzh, qzl, qzTh, sts, mask,
                                       A2h, A2l);
    mm_fz_kernel<<<1024, 256, 0, stream>>>(A1h, A1l, A2h, A2l, T1ph, T1pl,
                                           T2ph, T2pl, F1p, F2p);
    fzqg_kernel<<<128, 256, 0, stream>>>(x, F1p, F2p, qz_f, qzh, qzl, gw,
                                         mask, out, iter == NITER - 1);
  }
}

// Round 14
// 294.095 us; speedup vs baseline: 1.0961x; 1.0961x over previous
//
#include <hip/hip_runtime.h>
#include <hip/hip_bf16.h>

#define BB 8
#define LL 512
#define CC 8
#define NITER 3
#define NP 8  // split-K parts for mm_fz

typedef __attribute__((ext_vector_type(8))) short bf16x8;
typedef __attribute__((ext_vector_type(4))) float f32x4;
typedef unsigned short u16;

#define MFMA(A, B, C) __builtin_amdgcn_mfma_f32_16x16x32_bf16(A, B, C, 0, 0, 0)

__device__ inline u16 f2b(float f) {
  __hip_bfloat16 h = __float2bfloat16(f);
  return *reinterpret_cast<u16*>(&h);
}
__device__ inline float b2f(u16 u) {
  __hip_bfloat16 h;
  *reinterpret_cast<u16*>(&h) = u;
  return __bfloat162float(h);
}
__device__ inline void split2(float v, u16& hi, u16& lo) {
  hi = f2b(v);
  lo = f2b(v - b2f(hi));
}

// Stage a [64][64] bf16 tile (row stride ld) into LDS, XOR-swizzled.
__device__ inline void stageT(u16* lds, const u16* __restrict__ src, int ld,
                              int t, int nthr) {
  for (int ch = t; ch < 512; ch += nthr) {
    int r = ch >> 3, seg = ch & 7;
    int byte = (r * 128 + seg * 16) ^ ((r & 7) << 4);
    *(bf16x8*)((char*)lds + byte) = *(const bf16x8*)(src + r * ld + seg * 8);
  }
}
// mfma_16x16x32 operand fragment from swizzled tile: rows row0..row0+15.
__device__ inline bf16x8 frag64(const u16* lds, int row0, int ks, int lane) {
  int r = row0 + (lane & 15);
  int byte = (r * 128 + ks * 64 + ((lane >> 4) << 4)) ^ ((r & 7) << 4);
  return *(const bf16x8*)((const char*)lds + byte);
}
// split-precision accumulate: acc += Ah*Bh + Ah*Bl + Al*Bh
__device__ inline void mfma3(f32x4& acc, bf16x8 ah, bf16x8 al, bf16x8 bh,
                             bf16x8 bl) {
  acc = MFMA(ah, bh, acc);
  acc = MFMA(ah, bl, acc);
  acc = MFMA(al, bh, acc);
}

#define ACC_INIT {{0.f,0.f,0.f,0.f},{0.f,0.f,0.f,0.f},{0.f,0.f,0.f,0.f},{0.f,0.f,0.f,0.f}}

// ---------------------------------------------------------------------------
// repack ternary to split pairs: TB[k,c][e][a], T1p[a][k,c,e], T2p[e][k,c,a]
// ---------------------------------------------------------------------------
__global__ __launch_bounds__(256) void repack_kernel(
    const float* __restrict__ T, u16* TBh, u16* TBl, u16* T1h, u16* T1l,
    u16* T2h, u16* T2l) {
  int tid = blockIdx.x * 256 + threadIdx.x;  // [2][64][64][8]
  int c = tid & 7, e = (tid >> 3) & 63, a = (tid >> 9) & 63, kk = tid >> 15;
  u16 hi, lo;
  split2(T[tid], hi, lo);
  int iTB = ((kk * 8 + c) * 64 + e) * 64 + a;
  int i1 = a * 1024 + kk * 512 + c * 64 + e;
  int i2 = e * 1024 + kk * 512 + c * 64 + a;
  TBh[iTB] = hi; TBl[iTB] = lo;
  T1h[i1] = hi;  T1l[i1] = lo;
  T2h[i2] = hi;  T2l[i2] = lo;
}

// ---------------------------------------------------------------------------
// q_z = softmax(x) * m1 ; fp32 + split-bf16 copies  (iteration 0 only)
// ---------------------------------------------------------------------------
__global__ __launch_bounds__(64) void softmax_z_kernel(
    const float* __restrict__ in, const int* __restrict__ mask,
    float* __restrict__ qz, u16* __restrict__ qzh, u16* __restrict__ qzl) {
  int row = blockIdx.x;
  int t = threadIdx.x;
  float v = in[row * 64 + t];
  float m = v;
  for (int o = 32; o; o >>= 1) m = fmaxf(m, __shfl_xor(m, o));
  float e = __expf(v - m);
  float s = e;
  for (int o = 32; o; o >>= 1) s += __shfl_xor(s, o);
  float mi = (mask[row] != 0) ? 1.f : 0.f;
  float r = e / s * mi;
  qz[row * 64 + t] = r;
  u16 hi, lo;
  split2(r, hi, lo);
  qzh[row * 64 + t] = hi;
  qzl[row * 64 + t] = lo;
}

// ---------------------------------------------------------------------------
// fused: blk<1024 -> t1[kk,b,c][i][e] = sum_a qz[b,i,a]*T[kk,a,e,c]
//        blk>=1024 -> qzT[b][a][i] = qz[b][i][a]  (hi and lo)
// ---------------------------------------------------------------------------
__global__ __launch_bounds__(256) void t1qzT_kernel(
    const u16* __restrict__ qzh, const u16* __restrict__ qzl,
    const u16* __restrict__ TBh, const u16* __restrict__ TBl,
    u16* __restrict__ t1h, u16* __restrict__ t1l, u16* __restrict__ qzTh,
    u16* __restrict__ qzTl) {
  __shared__ u16 smem[16384];  // 32 KB, aliased by both paths
  int blk = blockIdx.x;
  int t = threadIdx.x;
  if (blk >= 1024) {
    int blk2 = blk - 1024;  // sel*64 + b*8 + it
    int it = blk2 & 7, b = (blk2 >> 3) & 7, sel = blk2 >> 6;
    const u16* src = sel ? qzl : qzh;
    u16* dst = sel ? qzTl : qzTh;
    u16(*s)[65] = (u16(*)[65])smem;
    for (int p = t; p < 4096; p += 256) {
      int r = p >> 6, a = p & 63;
      s[r][a] = src[(b * 512 + it * 64 + r) * 64 + a];
    }
    __syncthreads();
    for (int p = t; p < 4096; p += 256) {
      int a = p >> 6, i = p & 63;
      dst[(b * 64 + a) * 512 + it * 64 + i] = s[i][a];
    }
    return;
  }
  int it = blk & 7, c = (blk >> 3) & 7, b = (blk >> 6) & 7, kk = blk >> 9;
  u16* ah_s = smem;
  u16* al_s = smem + 4096;
  u16* bh_s = smem + 8192;
  u16* bl_s = smem + 12288;
  int lane = t & 63, w = t >> 6;
  stageT(ah_s, qzh + (b * 512 + it * 64) * 64, 64, t, 256);
  stageT(al_s, qzl + (b * 512 + it * 64) * 64, 64, t, 256);
  stageT(bh_s, TBh + (kk * 8 + c) * 4096, 64, t, 256);
  stageT(bl_s, TBl + (kk * 8 + c) * 4096, 64, t, 256);
  __syncthreads();
  f32x4 acc[4] = ACC_INIT;
  for (int ks = 0; ks < 2; ks++) {
    bf16x8 ah = frag64(ah_s, w * 16, ks, lane);
    bf16x8 al = frag64(al_s, w * 16, ks, lane);
#pragma unroll
    for (int nt = 0; nt < 4; nt++)
      mfma3(acc[nt], ah, al, frag64(bh_s, nt * 16, ks, lane),
            frag64(bl_s, nt * 16, ks, lane));
  }
  size_t base = ((size_t)((kk * 8 + b) * 8 + c)) * 32768;
  int rb = (lane >> 4) * 4, cl = lane & 15;
#pragma unroll
  for (int nt = 0; nt < 4; nt++)
#pragma unroll
    for (int r = 0; r < 4; r++) {
      size_t o = base + (size_t)(it * 64 + w * 16 + rb + r) * 64 + nt * 16 + cl;
      u16 h, l;
      split2(acc[nt][r], h, l);
      t1h[o] = h;
      t1l[o] = l;
    }
}

// ---------------------------------------------------------------------------
// a1: fused no-max softmax + A1 = (qh*dm) @ qz.  Writes sts (denominators).
// GEMM2 B-operand is hi-only (qzT-lo dropped: below A-side bf16 noise floor).
// 512 threads: wave w -> row-group rg=w&3 (16 rows), col-half nh=w>>2.
// ---------------------------------------------------------------------------
#define A1_PASS(TFH, TFL, ACC, KKis0)                                        \
  {                                                                          \
    f32x4 accq0 = {0.f, 0.f, 0.f, 0.f}, accq1 = {0.f, 0.f, 0.f, 0.f};       \
    _Pragma("unroll") for (int ks = 0; ks < 2; ks++) {                       \
      bf16x8 bh0 = frag64(bx0, (nh * 2) * 16, ks, lane);                     \
      bf16x8 bl0 = frag64(bx1, (nh * 2) * 16, ks, lane);                     \
      bf16x8 bh1 = frag64(bx0, (nh * 2 + 1) * 16, ks, lane);                 \
      bf16x8 bl1 = frag64(bx1, (nh * 2 + 1) * 16, ks, lane);                 \
      accq0 = MFMA(TFH[ks], bh0, accq0);                                     \
      accq0 = MFMA(TFH[ks], bl0, accq0);                                     \
      accq0 = MFMA(TFL[ks], bh0, accq0);                                     \
      accq1 = MFMA(TFH[ks], bh1, accq1);                                     \
      accq1 = MFMA(TFH[ks], bl1, accq1);                                     \
      accq1 = MFMA(TFL[ks], bh1, accq1);                                     \
    }                                                                        \
    _Pragma("unroll") for (int ntl = 0; ntl < 2; ntl++) {                    \
      int col = (nh * 2 + ntl) * 16 + cl;                                    \
      int jg = jt * 64 + col;                                                \
      float mj = (mask[b * 512 + jg] != 0) ? 1.f : 0.f;                      \
      _Pragma("unroll") for (int r = 0; r < 4; r++) {                        \
        int row = rg * 16 + g * 4 + r;                                       \
        int ig = it * 64 + row;                                              \
        float e = __expf(ntl ? accq1[r] : accq0[r]);                         \
        float es, q;                                                         \
        if (KKis0) {                                                         \
          es = (jg > ig) ? e : ((jg == ig) ? 1.f : 0.f);                     \
          q = (jg > ig) ? e * mj : 0.f;                                      \
        } else {                                                             \
          es = (jg < ig) ? e : 0.f;                                          \
          q = (jg < ig) ? e * mj : 0.f;                                      \
        }                                                                    \
        s_run[r] += es;                                                      \
        int byte = (row * 128 + col * 2) ^ ((row & 7) << 4);                 \
        *(u16*)((char*)qh_s + byte) = f2b(q);                                \
      }                                                                      \
    }                                                                        \
    __syncthreads();                                                         \
    _Pragma("unroll") for (int ks = 0; ks < 2; ks++) {                       \
      bf16x8 ah = frag64(qh_s, rg * 16, ks, lane);                           \
      _Pragma("unroll") for (int ntl = 0; ntl < 2; ntl++) {                  \
        int nt = nh * 2 + ntl;                                               \
        bf16x8 bh = frag64(bt0, nt * 16, ks, lane);                          \
        ACC[ntl] = MFMA(ah, bh, ACC[ntl]);                                   \
      }                                                                      \
    }                                                                        \
  }

__global__ __launch_bounds__(512, 4) void a1_kernel(
    const u16* __restrict__ t1h, const u16* __restrict__ t1l,
    const u16* __restrict__ qzh, const u16* __restrict__ qzl,
    const u16* __restrict__ qzTh, const int* __restrict__ mask,
    float* __restrict__ sts, u16* __restrict__ A1h, u16* __restrict__ A1l) {
  int blk = blockIdx.x;  // b*64 + c*8 + it
  int it = blk & 7, c = (blk >> 3) & 7, b = blk >> 6;
  __shared__ u16 smem[16640];  // 33280 B
  u16* bx0 = smem;             // qz[jt] hi
  u16* bx1 = smem + 4096;      // qz[jt] lo
  u16* bt0 = smem + 8192;      // qzT hi
  u16* qh_s = smem + 12288;    // qh hi
  float* ps = (float*)(smem + 16384);  // [2][64]
  int t = threadIdx.x, lane = t & 63, w = t >> 6, cl = lane & 15, g = lane >> 4;
  int rg = w & 3, nh = w >> 2;
  const size_t KSTR = (size_t)64 * 32768;
  size_t tb = ((size_t)(b * 8 + c)) * 32768 + it * 4096;
  // prologue: stage both t1 tiles (kk0 hi/lo, kk1 hi/lo), hoist A-frags
  stageT(bx0, t1h + tb, 64, t, 512);
  stageT(bx1, t1l + tb, 64, t, 512);
  stageT(bt0, t1h + tb + KSTR, 64, t, 512);
  stageT(qh_s, t1l + tb + KSTR, 64, t, 512);
  __syncthreads();
  bf16x8 tf0h[2], tf0l[2], tf1h[2], tf1l[2];
#pragma unroll
  for (int ks = 0; ks < 2; ks++) {
    tf0h[ks] = frag64(bx0, rg * 16, ks, lane);
    tf0l[ks] = frag64(bx1, rg * 16, ks, lane);
    tf1h[ks] = frag64(bt0, rg * 16, ks, lane);
    tf1l[ks] = frag64(qh_s, rg * 16, ks, lane);
  }
  float mi_[4], s_run[4];
#pragma unroll
  for (int r = 0; r < 4; r++) {
    mi_[r] = (mask[b * 512 + it * 64 + rg * 16 + g * 4 + r] != 0) ? 1.f : 0.f;
    s_run[r] = 0.f;
  }
  f32x4 accU[2] = {{0.f, 0.f, 0.f, 0.f}, {0.f, 0.f, 0.f, 0.f}};
  f32x4 accL[2] = {{0.f, 0.f, 0.f, 0.f}, {0.f, 0.f, 0.f, 0.f}};

#pragma unroll 1
  for (int jt = 0; jt < 8; jt++) {
    __syncthreads();  // protects hoist reads (jt=0) / prior GEMM reads
    stageT(bx0, qzh + (b * 512 + jt * 64) * 64, 64, t, 512);
    stageT(bx1, qzl + (b * 512 + jt * 64) * 64, 64, t, 512);
    stageT(bt0, qzTh + (size_t)b * 32768 + jt * 64, 512, t, 512);
    __syncthreads();
    if (jt > it) {
      A1_PASS(tf0h, tf0l, accU, true)
    } else if (jt < it) {
      A1_PASS(tf1h, tf1l, accL, false)
    } else {
      A1_PASS(tf0h, tf0l, accU, true)
      __syncthreads();  // qh_s rewrite vs GEMM2 reads
      A1_PASS(tf1h, tf1l, accL, false)
    }
  }
  // epilogue: one reduction for s, then scale + store
#pragma unroll
  for (int r = 0; r < 4; r++) {
    float s = s_run[r];
    s += __shfl_xor(s, 1);
    s += __shfl_xor(s, 2);
    s += __shfl_xor(s, 4);
    s += __shfl_xor(s, 8);
    s_run[r] = s;
  }
  __syncthreads();
  if (cl == 0) {
#pragma unroll
    for (int r = 0; r < 4; r++) ps[nh * 64 + rg * 16 + g * 4 + r] = s_run[r];
  }
  __syncthreads();
#pragma unroll
  for (int r = 0; r < 4; r++) {
    int row = rg * 16 + g * 4 + r;
    float stot = ps[row] + ps[64 + row];
    float scale = mi_[r] / stot;
    int grow = it * 64 + row;
#pragma unroll
    for (int ntl = 0; ntl < 2; ntl++) {
      size_t o0 = ((size_t)b * 512 + grow) * 1024 + c * 64 +
                  (nh * 2 + ntl) * 16 + cl;
      u16 h, l;
      split2(accU[ntl][r] * scale, h, l);
      A1h[o0] = h;
      A1l[o0] = l;
      split2(accL[ntl][r] * scale, h, l);
      A1h[o0 + 512] = h;
      A1l[o0 + 512] = l;
    }
    if (nh == 0 && cl == 0) sts[(b * 8 + c) * 512 + grow] = stot;
  }
}

// ---------------------------------------------------------------------------
// a2: A2[b][j][kk,c,a] = sum_i qh[kk][i][j]·qz[i][a]  (recompute, uses sts)
// GEMM2 B-operand hi-only.
// ---------------------------------------------------------------------------
#define A2_PASS(ACC, KKis0)                                                  \
  {                                                                          \
    f32x4 accq0 = {0.f, 0.f, 0.f, 0.f}, accq1 = {0.f, 0.f, 0.f, 0.f};       \
    _Pragma("unroll") for (int ks = 0; ks < 2; ks++) {                       \
      bf16x8 bh0 = frag64(tsx0, (nh * 2) * 16, ks, lane);                    \
      bf16x8 bl0 = frag64(tsx1, (nh * 2) * 16, ks, lane);                    \
      bf16x8 bh1 = frag64(tsx0, (nh * 2 + 1) * 16, ks, lane);                \
      bf16x8 bl1 = frag64(tsx1, (nh * 2 + 1) * 16, ks, lane);                \
      accq0 = MFMA(afh[ks], bh0, accq0);                                     \
      accq0 = MFMA(afh[ks], bl0, accq0);                                     \
      accq0 = MFMA(afl[ks], bh0, accq0);                                     \
      accq1 = MFMA(afh[ks], bh1, accq1);                                     \
      accq1 = MFMA(afh[ks], bl1, accq1);                                     \
      accq1 = MFMA(afl[ks], bh1, accq1);                                     \
    }                                                                        \
    _Pragma("unroll") for (int ntl = 0; ntl < 2; ntl++) {                    \
      int col = (nh * 2 + ntl) * 16 + cl;                                    \
      int ig = ii * 64 + col;                                                \
      float sim = simi[col];                                                 \
      _Pragma("unroll") for (int r = 0; r < 4; r++) {                        \
        int row = rg * 16 + g * 4 + r;                                       \
        int jg = jt * 64 + row;                                              \
        float e = __expf(ntl ? accq1[r] : accq0[r]);                         \
        bool keep = KKis0 ? (jg > ig) : (jg < ig);                           \
        float q = keep ? e * sim * mjrow[r] : 0.f;                           \
        int byte = (row * 128 + col * 2) ^ ((row & 7) << 4);                 \
        *(u16*)((char*)qh_s + byte) = f2b(q);                                \
      }                                                                      \
    }                                                                        \
    __syncthreads();                                                         \
    _Pragma("unroll") for (int ks = 0; ks < 2; ks++) {                       \
      bf16x8 ah = frag64(qh_s, rg * 16, ks, lane);                           \
      _Pragma("unroll") for (int ntl = 0; ntl < 2; ntl++) {                  \
        int nt = nh * 2 + ntl;                                               \
        bf16x8 bh = frag64(bt0, nt * 16, ks, lane);                          \
        ACC[ntl] = MFMA(ah, bh, ACC[ntl]);                                   \
      }                                                                      \
    }                                                                        \
  }

__global__ __launch_bounds__(512, 4) void a2_kernel(
    const u16* __restrict__ t1h, const u16* __restrict__ t1l,
    const u16* __restrict__ qzh, const u16* __restrict__ qzl,
    const u16* __restrict__ qzTh, const float* __restrict__ sts,
    const int* __restrict__ mask, u16* __restrict__ A2h,
    u16* __restrict__ A2l) {
  int blk = blockIdx.x;  // b*64 + c*8 + jt
  int jt = blk & 7, c = (blk >> 3) & 7, b = blk >> 6;
  __shared__ u16 smem[16512];  // 33024 B
  u16* tsx0 = smem;            // t1 tile hi
  u16* tsx1 = smem + 4096;     // t1 tile lo
  u16* bt0 = smem + 8192;      // qzT hi
  u16* qh_s = smem + 12288;    // qhT hi
  float* simi = (float*)(smem + 16384);  // [64] = mi/s per i
  int t = threadIdx.x, lane = t & 63, w = t >> 6, cl = lane & 15, g = lane >> 4;
  int rg = w & 3, nh = w >> 2;
  const size_t KSTR = (size_t)64 * 32768;
  size_t tbb = ((size_t)(b * 8 + c)) * 32768;
  // prologue: stage qz[jt] into tsx area, hoist A-frags
  stageT(tsx0, qzh + (b * 512 + jt * 64) * 64, 64, t, 512);
  stageT(tsx1, qzl + (b * 512 + jt * 64) * 64, 64, t, 512);
  __syncthreads();
  bf16x8 afh[2], afl[2];
#pragma unroll
  for (int ks = 0; ks < 2; ks++) {
    afh[ks] = frag64(tsx0, rg * 16, ks, lane);
    afl[ks] = frag64(tsx1, rg * 16, ks, lane);
  }
  float mjrow[4];
#pragma unroll
  for (int r = 0; r < 4; r++) {
    int jg = jt * 64 + rg * 16 + g * 4 + r;
    mjrow[r] = (mask[b * 512 + jg] != 0) ? 1.f : 0.f;
  }
  f32x4 accU[2] = {{0.f, 0.f, 0.f, 0.f}, {0.f, 0.f, 0.f, 0.f}};
  f32x4 accL[2] = {{0.f, 0.f, 0.f, 0.f}, {0.f, 0.f, 0.f, 0.f}};

#pragma unroll 1
  for (int ii = 0; ii < 8; ii++) {
    int diag = (ii == jt);
    int kk0 = (ii < jt) ? 0 : 1;
    __syncthreads();
    {
      size_t tsrc = tbb + ii * 4096 + ((diag || kk0 == 0) ? 0 : KSTR);
      stageT(tsx0, t1h + tsrc, 64, t, 512);
      stageT(tsx1, t1l + tsrc, 64, t, 512);
    }
    stageT(bt0, qzTh + (size_t)b * 32768 + ii * 64, 512, t, 512);
    if (t < 64) {
      int ig = ii * 64 + t;
      float mi = (mask[b * 512 + ig] != 0) ? 1.f : 0.f;
      simi[t] = mi / sts[(b * 8 + c) * 512 + ig];
    }
    __syncthreads();
    if (diag) {
      A2_PASS(accU, true)
      __syncthreads();
      stageT(tsx0, t1h + tbb + ii * 4096 + KSTR, 64, t, 512);
      stageT(tsx1, t1l + tbb + ii * 4096 + KSTR, 64, t, 512);
      __syncthreads();
      A2_PASS(accL, false)
    } else if (kk0 == 0) {
      A2_PASS(accU, true)
    } else {
      A2_PASS(accL, false)
    }
  }
#pragma unroll
  for (int r = 0; r < 4; r++) {
    int row = jt * 64 + rg * 16 + g * 4 + r;
#pragma unroll
    for (int ntl = 0; ntl < 2; ntl++) {
      size_t o0 = ((size_t)b * 512 + row) * 1024 + c * 64 +
                  (nh * 2 + ntl) * 16 + cl;
      u16 h, l;
      split2(accU[ntl][r], h, l);
      A2h[o0] = h;
      A2l[o0] = l;
      split2(accL[ntl][r], h, l);
      A2h[o0 + 512] = h;
      A2l[o0 + 512] = l;
    }
  }
}

// ---------------------------------------------------------------------------
// F{1,2} partials: Fp[part][b][m][n] = sum_{K part} A[b][m][K]·Tp[n][K]
// blk = sel*512 + part*64 + b*8 + it  (sel: 0->F1, 1->F2)
// ---------------------------------------------------------------------------
__global__ __launch_bounds__(256) void mm_fz_kernel(
    const u16* __restrict__ A1h, const u16* __restrict__ A1l,
    const u16* __restrict__ A2h, const u16* __restrict__ A2l,
    const u16* __restrict__ T1ph, const u16* __restrict__ T1pl,
    const u16* __restrict__ T2ph, const u16* __restrict__ T2pl,
    float* __restrict__ F1p, float* __restrict__ F2p) {
  int blk = blockIdx.x;
  int it = blk & 7, b = (blk >> 3) & 7, part = (blk >> 6) & 7, sel = blk >> 9;
  const u16* Ah = sel ? A2h : A1h;
  const u16* Al = sel ? A2l : A1l;
  const u16* Bh = sel ? T2ph : T1ph;
  const u16* Bl = sel ? T2pl : T1pl;
  float* Fp = (sel ? F2p : F1p) + (size_t)part * (BB * 512 * 64);
  __shared__ u16 ah_s[4096], al_s[4096], bh_s[4096], bl_s[4096];
  int t = threadIdx.x, lane = t & 63, w = t >> 6;
  f32x4 acc[4] = ACC_INIT;
  size_t abase = ((size_t)b * 512 + it * 64) * 1024;
  for (int cc2 = 0; cc2 < 2; cc2++) {
    int ch = part * 2 + cc2;
    __syncthreads();
    stageT(ah_s, Ah + abase + ch * 64, 1024, t, 256);
    stageT(al_s, Al + abase + ch * 64, 1024, t, 256);
    stageT(bh_s, Bh + ch * 64, 1024, t, 256);
    stageT(bl_s, Bl + ch * 64, 1024, t, 256);
    __syncthreads();
    for (int ks = 0; ks < 2; ks++) {
      bf16x8 ah = frag64(ah_s, w * 16, ks, lane);
      bf16x8 al = frag64(al_s, w * 16, ks, lane);
#pragma unroll
      for (int nt = 0; nt < 4; nt++)
        mfma3(acc[nt], ah, al, frag64(bh_s, nt * 16, ks, lane),
              frag64(bl_s, nt * 16, ks, lane));
    }
  }
  int rb = (lane >> 4) * 4, cl = lane & 15;
#pragma unroll
  for (int nt = 0; nt < 4; nt++)
#pragma unroll
    for (int r = 0; r < 4; r++)
      Fp[((size_t)b * 512 + it * 64 + w * 16 + rb + r) * 64 + nt * 16 + cl] =
          acc[nt][r];
}

// ---------------------------------------------------------------------------
// fused q_g + F_Z (+ Z-softmax for non-final iters)
// ---------------------------------------------------------------------------
__global__ __launch_bounds__(256) void fzqg_kernel(
    const float* __restrict__ x, const float* __restrict__ F1p,
    const float* __restrict__ F2p, float* __restrict__ qz,
    u16* __restrict__ qzh, u16* __restrict__ qzl, const float* __restrict__ gw,
    const int* __restrict__ mask, float* __restrict__ out, int final_) {
  int blk = blockIdx.x;
  int ic = blk & 15, b = blk >> 4;
  int i0 = ic * 32;
  int t = threadIdx.x;
  __shared__ float gw_s[64][65];
  __shared__ float qz_s[32][64];
  __shared__ float fg_s[32][65];
  for (int p = t; p < 4096; p += 256) gw_s[p >> 6][p & 63] = gw[p];
  for (int p = t; p < 2048; p += 256) {
    int il = p >> 6, a = p & 63;
    qz_s[il][a] = qz[(b * LL + i0 + il) * 64 + a];
  }
  __syncthreads();
  int gcol = t & 63, il0 = t >> 6;
#pragma unroll
  for (int s = 0; s < 8; s++) {
    int il = il0 + 4 * s;
    float acc = 0.f;
    for (int a = 0; a < 64; a++) acc += qz_s[il][a] * gw_s[gcol][a];
    fg_s[il][gcol] = acc;
  }
  __syncthreads();
  {
    int r = t >> 3, k = t & 7;
    float v[8];
#pragma unroll
    for (int u = 0; u < 8; u++) v[u] = fg_s[r][k * 8 + u];
    float m = v[0];
#pragma unroll
    for (int u = 1; u < 8; u++) m = fmaxf(m, v[u]);
    for (int o = 1; o < 8; o <<= 1) m = fmaxf(m, __shfl_xor(m, o));
    float s = 0.f;
#pragma unroll
    for (int u = 0; u < 8; u++) s += __expf(v[u] - m);
    for (int o = 1; o < 8; o <<= 1) s += __shfl_xor(s, o);
    float mi = (mask[b * LL + i0 + r] != 0) ? 1.f : 0.f;
    float inv = mi / s;
#pragma unroll
    for (int u = 0; u < 8; u++) fg_s[r][k * 8 + u] = __expf(v[u] - m) * inv;
  }
  __syncthreads();
  int a = t & 63;
#pragma unroll
  for (int s = 0; s < 8; s++) {
    int il = il0 + 4 * s;
    float acc = 0.f;
    for (int g2 = 0; g2 < 64; g2++) acc += fg_s[il][g2] * gw_s[g2][a];
    size_t idx = (size_t)(b * LL + i0 + il) * 64 + a;
    float fs = x[idx] + acc;
    for (int p = 0; p < NP; p++)
      fs += F1p[(size_t)p * (BB * 512 * 64) + idx] +
            F2p[(size_t)p * (BB * 512 * 64) + idx];
    if (final_) {
      out[idx] = fs;
    } else {
      float m = fs;
      for (int o = 32; o; o >>= 1) m = fmaxf(m, __shfl_xor(m, o));
      float e = __expf(fs - m);
      float ss = e;
      for (int o = 32; o; o >>= 1) ss += __shfl_xor(ss, o);
      float mi = (mask[b * LL + i0 + il] != 0) ? 1.f : 0.f;
      float r = e / ss * mi;
      qz[idx] = r;
      u16 hi, lo;
      split2(r, hi, lo);
      qzh[idx] = hi;
      qzl[idx] = lo;
    }
  }
}

// ---------------------------------------------------------------------------
extern "C" void kernel_launch(void* const* d_in, const int* in_sizes, int n_in,
                              void* d_out, int out_size, void* d_ws,
                              size_t ws_size, hipStream_t stream) {
  const float* x = (const float*)d_in[0];
  const int* mask = (const int*)d_in[1];
  const float* ternary = (const float*)d_in[2];
  const float* gw = (const float*)d_in[3];
  float* out = (float*)d_out;

  char* w = (char*)d_ws;
  float* qz_f = (float*)(w);                           // 1 MB
  u16* qzh = (u16*)(w + (2 << 20));                    // 512 KB
  u16* qzl = (u16*)(w + (2 << 20) + (512 << 10));      // 512 KB
  u16* qzTh = (u16*)(w + (3 << 20));                   // 512 KB
  u16* qzTl = (u16*)(w + (3 << 20) + (512 << 10));     // 512 KB
  u16* TBh = (u16*)(w + (4 << 20));                    // 6 x 128 KB
  u16* TBl = (u16*)(w + (4 << 20) + (128 << 10));
  u16* T1ph = (u16*)(w + (4 << 20) + (256 << 10));
  u16* T1pl = (u16*)(w + (4 << 20) + (384 << 10));
  u16* T2ph = (u16*)(w + (4 << 20) + (512 << 10));
  u16* T2pl = (u16*)(w + (4 << 20) + (640 << 10));
  float* sts = (float*)(w + (5 << 20));                // 128 KB
  float* F1p = (float*)(w + (6 << 20));                // 8 MB
  float* F2p = (float*)(w + (14 << 20));               // 8 MB
  u16* t1h = (u16*)(w + (22 << 20));                   // 8 MB
  u16* t1l = (u16*)(w + (30 << 20));                   // 8 MB
  u16* A1h = (u16*)(w + (38 << 20));                   // 8 MB
  u16* A1l = (u16*)(w + (46 << 20));                   // 8 MB
  u16* A2h = (u16*)(w + (54 << 20));                   // 8 MB
  u16* A2l = (u16*)(w + (62 << 20));                   // 8 MB -> 70 MB total

  repack_kernel<<<256, 256, 0, stream>>>(ternary, TBh, TBl, T1ph, T1pl, T2ph,
                                         T2pl);
  softmax_z_kernel<<<BB * LL, 64, 0, stream>>>(x, mask, qz_f, qzh, qzl);
  for (int iter = 0; iter < NITER; iter++) {
    t1qzT_kernel<<<1152, 256, 0, stream>>>(qzh, qzl, TBh, TBl, t1h, t1l, qzTh,
                                           qzTl);
    a1_kernel<<<512, 512, 0, stream>>>(t1h, t1l, qzh, qzl, qzTh, mask, sts,
                                       A1h, A1l);
    a2_kernel<<<512, 512, 0, stream>>>(t1h, t1l, qzh, qzl, qzTh, sts, mask,
                                       A2h, A2l);
    mm_fz_kernel<<<1024, 256, 0, stream>>>(A1h, A1l, A2h, A2l, T1ph, T1pl,
                                           T2ph, T2pl, F1p, F2p);
    fzqg_kernel<<<128, 256, 0, stream>>>(x, F1p, F2p, qz_f, qzh, qzl, gw,
                                         mask, out, iter == NITER - 1);
  }
}

// Round 15
// 274.824 us; speedup vs baseline: 1.1730x; 1.0701x over previous
//
#include <hip/hip_runtime.h>
#include <hip/hip_bf16.h>

#define BB 8
#define LL 512
#define CC 8
#define NITER 3
#define NP 8  // split-K parts for mm_fz

typedef __attribute__((ext_vector_type(8))) short bf16x8;
typedef __attribute__((ext_vector_type(4))) float f32x4;
typedef unsigned short u16;

#define MFMA(A, B, C) __builtin_amdgcn_mfma_f32_16x16x32_bf16(A, B, C, 0, 0, 0)

__device__ inline u16 f2b(float f) {
  __hip_bfloat16 h = __float2bfloat16(f);
  return *reinterpret_cast<u16*>(&h);
}
__device__ inline float b2f(u16 u) {
  __hip_bfloat16 h;
  *reinterpret_cast<u16*>(&h) = u;
  return __bfloat162float(h);
}
__device__ inline void split2(float v, u16& hi, u16& lo) {
  hi = f2b(v);
  lo = f2b(v - b2f(hi));
}

// Stage a [64][64] bf16 tile (row stride ld) into LDS, XOR-swizzled.
__device__ inline void stageT(u16* lds, const u16* __restrict__ src, int ld,
                              int t, int nthr) {
  for (int ch = t; ch < 512; ch += nthr) {
    int r = ch >> 3, seg = ch & 7;
    int byte = (r * 128 + seg * 16) ^ ((r & 7) << 4);
    *(bf16x8*)((char*)lds + byte) = *(const bf16x8*)(src + r * ld + seg * 8);
  }
}
// mfma_16x16x32 operand fragment from swizzled tile: rows row0..row0+15.
__device__ inline bf16x8 frag64(const u16* lds, int row0, int ks, int lane) {
  int r = row0 + (lane & 15);
  int byte = (r * 128 + ks * 64 + ((lane >> 4) << 4)) ^ ((r & 7) << 4);
  return *(const bf16x8*)((const char*)lds + byte);
}
// split-precision accumulate: acc += Ah*Bh + Ah*Bl + Al*Bh
__device__ inline void mfma3(f32x4& acc, bf16x8 ah, bf16x8 al, bf16x8 bh,
                             bf16x8 bl) {
  acc = MFMA(ah, bh, acc);
  acc = MFMA(ah, bl, acc);
  acc = MFMA(al, bh, acc);
}

#define ACC_INIT {{0.f,0.f,0.f,0.f},{0.f,0.f,0.f,0.f},{0.f,0.f,0.f,0.f},{0.f,0.f,0.f,0.f}}

// ---------------------------------------------------------------------------
// repack ternary: TB split pairs (logit path), T1p/T2p hi-only (mm_fz path).
// ---------------------------------------------------------------------------
__global__ __launch_bounds__(256) void repack_kernel(
    const float* __restrict__ T, u16* TBh, u16* TBl, u16* T1h, u16* T2h) {
  int tid = blockIdx.x * 256 + threadIdx.x;  // [2][64][64][8]
  int c = tid & 7, e = (tid >> 3) & 63, a = (tid >> 9) & 63, kk = tid >> 15;
  u16 hi, lo;
  split2(T[tid], hi, lo);
  int iTB = ((kk * 8 + c) * 64 + e) * 64 + a;
  int i1 = a * 1024 + kk * 512 + c * 64 + e;
  int i2 = e * 1024 + kk * 512 + c * 64 + a;
  TBh[iTB] = hi;
  TBl[iTB] = lo;
  T1h[i1] = hi;
  T2h[i2] = hi;
}

// ---------------------------------------------------------------------------
// q_z = softmax(x) * m1 ; fp32 + split-bf16 copies  (iteration 0 only)
// ---------------------------------------------------------------------------
__global__ __launch_bounds__(64) void softmax_z_kernel(
    const float* __restrict__ in, const int* __restrict__ mask,
    float* __restrict__ qz, u16* __restrict__ qzh, u16* __restrict__ qzl) {
  int row = blockIdx.x;
  int t = threadIdx.x;
  float v = in[row * 64 + t];
  float m = v;
  for (int o = 32; o; o >>= 1) m = fmaxf(m, __shfl_xor(m, o));
  float e = __expf(v - m);
  float s = e;
  for (int o = 32; o; o >>= 1) s += __shfl_xor(s, o);
  float mi = (mask[row] != 0) ? 1.f : 0.f;
  float r = e / s * mi;
  qz[row * 64 + t] = r;
  u16 hi, lo;
  split2(r, hi, lo);
  qzh[row * 64 + t] = hi;
  qzl[row * 64 + t] = lo;
}

// ---------------------------------------------------------------------------
// fused: blk<1024 -> t1[kk,b,c][i][e] = sum_a qz[b,i,a]*T[kk,a,e,c]
//        blk>=1024 -> qzT[b][a][i] = qz[b][i][a]  (hi and lo)
// ---------------------------------------------------------------------------
__global__ __launch_bounds__(256) void t1qzT_kernel(
    const u16* __restrict__ qzh, const u16* __restrict__ qzl,
    const u16* __restrict__ TBh, const u16* __restrict__ TBl,
    u16* __restrict__ t1h, u16* __restrict__ t1l, u16* __restrict__ qzTh,
    u16* __restrict__ qzTl) {
  __shared__ u16 smem[16384];  // 32 KB, aliased by both paths
  int blk = blockIdx.x;
  int t = threadIdx.x;
  if (blk >= 1024) {
    int blk2 = blk - 1024;  // sel*64 + b*8 + it
    int it = blk2 & 7, b = (blk2 >> 3) & 7, sel = blk2 >> 6;
    const u16* src = sel ? qzl : qzh;
    u16* dst = sel ? qzTl : qzTh;
    u16(*s)[65] = (u16(*)[65])smem;
    for (int p = t; p < 4096; p += 256) {
      int r = p >> 6, a = p & 63;
      s[r][a] = src[(b * 512 + it * 64 + r) * 64 + a];
    }
    __syncthreads();
    for (int p = t; p < 4096; p += 256) {
      int a = p >> 6, i = p & 63;
      dst[(b * 64 + a) * 512 + it * 64 + i] = s[i][a];
    }
    return;
  }
  int it = blk & 7, c = (blk >> 3) & 7, b = (blk >> 6) & 7, kk = blk >> 9;
  u16* ah_s = smem;
  u16* al_s = smem + 4096;
  u16* bh_s = smem + 8192;
  u16* bl_s = smem + 12288;
  int lane = t & 63, w = t >> 6;
  stageT(ah_s, qzh + (b * 512 + it * 64) * 64, 64, t, 256);
  stageT(al_s, qzl + (b * 512 + it * 64) * 64, 64, t, 256);
  stageT(bh_s, TBh + (kk * 8 + c) * 4096, 64, t, 256);
  stageT(bl_s, TBl + (kk * 8 + c) * 4096, 64, t, 256);
  __syncthreads();
  f32x4 acc[4] = ACC_INIT;
  for (int ks = 0; ks < 2; ks++) {
    bf16x8 ah = frag64(ah_s, w * 16, ks, lane);
    bf16x8 al = frag64(al_s, w * 16, ks, lane);
#pragma unroll
    for (int nt = 0; nt < 4; nt++)
      mfma3(acc[nt], ah, al, frag64(bh_s, nt * 16, ks, lane),
            frag64(bl_s, nt * 16, ks, lane));
  }
  size_t base = ((size_t)((kk * 8 + b) * 8 + c)) * 32768;
  int rb = (lane >> 4) * 4, cl = lane & 15;
#pragma unroll
  for (int nt = 0; nt < 4; nt++)
#pragma unroll
    for (int r = 0; r < 4; r++) {
      size_t o = base + (size_t)(it * 64 + w * 16 + rb + r) * 64 + nt * 16 + cl;
      u16 h, l;
      split2(acc[nt][r], h, l);
      t1h[o] = h;
      t1l[o] = l;
    }
}

// ---------------------------------------------------------------------------
// a1: fused no-max softmax + A1 = (qh*dm) @ qz.  Writes sts (denominators).
// GEMM2 B-operand hi-only; A1 output hi-only.
// 512 threads: wave w -> row-group rg=w&3 (16 rows), col-half nh=w>>2.
// ---------------------------------------------------------------------------
#define A1_PASS(TFH, TFL, ACC, KKis0)                                        \
  {                                                                          \
    f32x4 accq0 = {0.f, 0.f, 0.f, 0.f}, accq1 = {0.f, 0.f, 0.f, 0.f};       \
    _Pragma("unroll") for (int ks = 0; ks < 2; ks++) {                       \
      bf16x8 bh0 = frag64(bx0, (nh * 2) * 16, ks, lane);                     \
      bf16x8 bl0 = frag64(bx1, (nh * 2) * 16, ks, lane);                     \
      bf16x8 bh1 = frag64(bx0, (nh * 2 + 1) * 16, ks, lane);                 \
      bf16x8 bl1 = frag64(bx1, (nh * 2 + 1) * 16, ks, lane);                 \
      accq0 = MFMA(TFH[ks], bh0, accq0);                                     \
      accq0 = MFMA(TFH[ks], bl0, accq0);                                     \
      accq0 = MFMA(TFL[ks], bh0, accq0);                                     \
      accq1 = MFMA(TFH[ks], bh1, accq1);                                     \
      accq1 = MFMA(TFH[ks], bl1, accq1);                                     \
      accq1 = MFMA(TFL[ks], bh1, accq1);                                     \
    }                                                                        \
    _Pragma("unroll") for (int ntl = 0; ntl < 2; ntl++) {                    \
      int col = (nh * 2 + ntl) * 16 + cl;                                    \
      int jg = jt * 64 + col;                                                \
      float mj = (mask[b * 512 + jg] != 0) ? 1.f : 0.f;                      \
      _Pragma("unroll") for (int r = 0; r < 4; r++) {                        \
        int row = rg * 16 + g * 4 + r;                                       \
        int ig = it * 64 + row;                                              \
        float e = __expf(ntl ? accq1[r] : accq0[r]);                         \
        float es, q;                                                         \
        if (KKis0) {                                                         \
          es = (jg > ig) ? e : ((jg == ig) ? 1.f : 0.f);                     \
          q = (jg > ig) ? e * mj : 0.f;                                      \
        } else {                                                             \
          es = (jg < ig) ? e : 0.f;                                          \
          q = (jg < ig) ? e * mj : 0.f;                                      \
        }                                                                    \
        s_run[r] += es;                                                      \
        int byte = (row * 128 + col * 2) ^ ((row & 7) << 4);                 \
        *(u16*)((char*)qh_s + byte) = f2b(q);                                \
      }                                                                      \
    }                                                                        \
    __syncthreads();                                                         \
    _Pragma("unroll") for (int ks = 0; ks < 2; ks++) {                       \
      bf16x8 ah = frag64(qh_s, rg * 16, ks, lane);                           \
      _Pragma("unroll") for (int ntl = 0; ntl < 2; ntl++) {                  \
        int nt = nh * 2 + ntl;                                               \
        bf16x8 bh = frag64(bt0, nt * 16, ks, lane);                          \
        ACC[ntl] = MFMA(ah, bh, ACC[ntl]);                                   \
      }                                                                      \
    }                                                                        \
  }

__global__ __launch_bounds__(512, 4) void a1_kernel(
    const u16* __restrict__ t1h, const u16* __restrict__ t1l,
    const u16* __restrict__ qzh, const u16* __restrict__ qzl,
    const u16* __restrict__ qzTh, const int* __restrict__ mask,
    float* __restrict__ sts, u16* __restrict__ A1h) {
  int blk = blockIdx.x;  // b*64 + c*8 + it
  int it = blk & 7, c = (blk >> 3) & 7, b = blk >> 6;
  __shared__ u16 smem[16640];  // 33280 B
  u16* bx0 = smem;             // qz[jt] hi
  u16* bx1 = smem + 4096;      // qz[jt] lo
  u16* bt0 = smem + 8192;      // qzT hi
  u16* qh_s = smem + 12288;    // qh hi
  float* ps = (float*)(smem + 16384);  // [2][64]
  int t = threadIdx.x, lane = t & 63, w = t >> 6, cl = lane & 15, g = lane >> 4;
  int rg = w & 3, nh = w >> 2;
  const size_t KSTR = (size_t)64 * 32768;
  size_t tb = ((size_t)(b * 8 + c)) * 32768 + it * 4096;
  // prologue: stage both t1 tiles (kk0 hi/lo, kk1 hi/lo), hoist A-frags
  stageT(bx0, t1h + tb, 64, t, 512);
  stageT(bx1, t1l + tb, 64, t, 512);
  stageT(bt0, t1h + tb + KSTR, 64, t, 512);
  stageT(qh_s, t1l + tb + KSTR, 64, t, 512);
  __syncthreads();
  bf16x8 tf0h[2], tf0l[2], tf1h[2], tf1l[2];
#pragma unroll
  for (int ks = 0; ks < 2; ks++) {
    tf0h[ks] = frag64(bx0, rg * 16, ks, lane);
    tf0l[ks] = frag64(bx1, rg * 16, ks, lane);
    tf1h[ks] = frag64(bt0, rg * 16, ks, lane);
    tf1l[ks] = frag64(qh_s, rg * 16, ks, lane);
  }
  float mi_[4], s_run[4];
#pragma unroll
  for (int r = 0; r < 4; r++) {
    mi_[r] = (mask[b * 512 + it * 64 + rg * 16 + g * 4 + r] != 0) ? 1.f : 0.f;
    s_run[r] = 0.f;
  }
  f32x4 accU[2] = {{0.f, 0.f, 0.f, 0.f}, {0.f, 0.f, 0.f, 0.f}};
  f32x4 accL[2] = {{0.f, 0.f, 0.f, 0.f}, {0.f, 0.f, 0.f, 0.f}};

#pragma unroll 1
  for (int jt = 0; jt < 8; jt++) {
    __syncthreads();  // protects hoist reads (jt=0) / prior GEMM reads
    stageT(bx0, qzh + (b * 512 + jt * 64) * 64, 64, t, 512);
    stageT(bx1, qzl + (b * 512 + jt * 64) * 64, 64, t, 512);
    stageT(bt0, qzTh + (size_t)b * 32768 + jt * 64, 512, t, 512);
    __syncthreads();
    if (jt > it) {
      A1_PASS(tf0h, tf0l, accU, true)
    } else if (jt < it) {
      A1_PASS(tf1h, tf1l, accL, false)
    } else {
      A1_PASS(tf0h, tf0l, accU, true)
      __syncthreads();  // qh_s rewrite vs GEMM2 reads
      A1_PASS(tf1h, tf1l, accL, false)
    }
  }
  // epilogue: one reduction for s, then scale + store
#pragma unroll
  for (int r = 0; r < 4; r++) {
    float s = s_run[r];
    s += __shfl_xor(s, 1);
    s += __shfl_xor(s, 2);
    s += __shfl_xor(s, 4);
    s += __shfl_xor(s, 8);
    s_run[r] = s;
  }
  __syncthreads();
  if (cl == 0) {
#pragma unroll
    for (int r = 0; r < 4; r++) ps[nh * 64 + rg * 16 + g * 4 + r] = s_run[r];
  }
  __syncthreads();
#pragma unroll
  for (int r = 0; r < 4; r++) {
    int row = rg * 16 + g * 4 + r;
    float stot = ps[row] + ps[64 + row];
    float scale = mi_[r] / stot;
    int grow = it * 64 + row;
#pragma unroll
    for (int ntl = 0; ntl < 2; ntl++) {
      size_t o0 = ((size_t)b * 512 + grow) * 1024 + c * 64 +
                  (nh * 2 + ntl) * 16 + cl;
      A1h[o0] = f2b(accU[ntl][r] * scale);
      A1h[o0 + 512] = f2b(accL[ntl][r] * scale);
    }
    if (nh == 0 && cl == 0) sts[(b * 8 + c) * 512 + grow] = stot;
  }
}

// ---------------------------------------------------------------------------
// a2: A2[b][j][kk,c,a] = sum_i qh[kk][i][j]·qz[i][a]  (recompute, uses sts)
// GEMM2 B-operand hi-only; A2 output hi-only.
// ---------------------------------------------------------------------------
#define A2_PASS(ACC, KKis0)                                                  \
  {                                                                          \
    f32x4 accq0 = {0.f, 0.f, 0.f, 0.f}, accq1 = {0.f, 0.f, 0.f, 0.f};       \
    _Pragma("unroll") for (int ks = 0; ks < 2; ks++) {                       \
      bf16x8 bh0 = frag64(tsx0, (nh * 2) * 16, ks, lane);                    \
      bf16x8 bl0 = frag64(tsx1, (nh * 2) * 16, ks, lane);                    \
      bf16x8 bh1 = frag64(tsx0, (nh * 2 + 1) * 16, ks, lane);                \
      bf16x8 bl1 = frag64(tsx1, (nh * 2 + 1) * 16, ks, lane);                \
      accq0 = MFMA(afh[ks], bh0, accq0);                                     \
      accq0 = MFMA(afh[ks], bl0, accq0);                                     \
      accq0 = MFMA(afl[ks], bh0, accq0);                                     \
      accq1 = MFMA(afh[ks], bh1, accq1);                                     \
      accq1 = MFMA(afh[ks], bl1, accq1);                                     \
      accq1 = MFMA(afl[ks], bh1, accq1);                                     \
    }                                                                        \
    _Pragma("unroll") for (int ntl = 0; ntl < 2; ntl++) {                    \
      int col = (nh * 2 + ntl) * 16 + cl;                                    \
      int ig = ii * 64 + col;                                                \
      float sim = simi[col];                                                 \
      _Pragma("unroll") for (int r = 0; r < 4; r++) {                        \
        int row = rg * 16 + g * 4 + r;                                       \
        int jg = jt * 64 + row;                                              \
        float e = __expf(ntl ? accq1[r] : accq0[r]);                         \
        bool keep = KKis0 ? (jg > ig) : (jg < ig);                           \
        float q = keep ? e * sim * mjrow[r] : 0.f;                           \
        int byte = (row * 128 + col * 2) ^ ((row & 7) << 4);                 \
        *(u16*)((char*)qh_s + byte) = f2b(q);                                \
      }                                                                      \
    }                                                                        \
    __syncthreads();                                                         \
    _Pragma("unroll") for (int ks = 0; ks < 2; ks++) {                       \
      bf16x8 ah = frag64(qh_s, rg * 16, ks, lane);                           \
      _Pragma("unroll") for (int ntl = 0; ntl < 2; ntl++) {                  \
        int nt = nh * 2 + ntl;                                               \
        bf16x8 bh = frag64(bt0, nt * 16, ks, lane);                          \
        ACC[ntl] = MFMA(ah, bh, ACC[ntl]);                                   \
      }                                                                      \
    }                                                                        \
  }

__global__ __launch_bounds__(512, 4) void a2_kernel(
    const u16* __restrict__ t1h, const u16* __restrict__ t1l,
    const u16* __restrict__ qzh, const u16* __restrict__ qzl,
    const u16* __restrict__ qzTh, const float* __restrict__ sts,
    const int* __restrict__ mask, u16* __restrict__ A2h) {
  int blk = blockIdx.x;  // b*64 + c*8 + jt
  int jt = blk & 7, c = (blk >> 3) & 7, b = blk >> 6;
  __shared__ u16 smem[16512];  // 33024 B
  u16* tsx0 = smem;            // t1 tile hi
  u16* tsx1 = smem + 4096;     // t1 tile lo
  u16* bt0 = smem + 8192;      // qzT hi
  u16* qh_s = smem + 12288;    // qhT hi
  float* simi = (float*)(smem + 16384);  // [64] = mi/s per i
  int t = threadIdx.x, lane = t & 63, w = t >> 6, cl = lane & 15, g = lane >> 4;
  int rg = w & 3, nh = w >> 2;
  const size_t KSTR = (size_t)64 * 32768;
  size_t tbb = ((size_t)(b * 8 + c)) * 32768;
  // prologue: stage qz[jt] into tsx area, hoist A-frags
  stageT(tsx0, qzh + (b * 512 + jt * 64) * 64, 64, t, 512);
  stageT(tsx1, qzl + (b * 512 + jt * 64) * 64, 64, t, 512);
  __syncthreads();
  bf16x8 afh[2], afl[2];
#pragma unroll
  for (int ks = 0; ks < 2; ks++) {
    afh[ks] = frag64(tsx0, rg * 16, ks, lane);
    afl[ks] = frag64(tsx1, rg * 16, ks, lane);
  }
  float mjrow[4];
#pragma unroll
  for (int r = 0; r < 4; r++) {
    int jg = jt * 64 + rg * 16 + g * 4 + r;
    mjrow[r] = (mask[b * 512 + jg] != 0) ? 1.f : 0.f;
  }
  f32x4 accU[2] = {{0.f, 0.f, 0.f, 0.f}, {0.f, 0.f, 0.f, 0.f}};
  f32x4 accL[2] = {{0.f, 0.f, 0.f, 0.f}, {0.f, 0.f, 0.f, 0.f}};

#pragma unroll 1
  for (int ii = 0; ii < 8; ii++) {
    int diag = (ii == jt);
    int kk0 = (ii < jt) ? 0 : 1;
    __syncthreads();
    {
      size_t tsrc = tbb + ii * 4096 + ((diag || kk0 == 0) ? 0 : KSTR);
      stageT(tsx0, t1h + tsrc, 64, t, 512);
      stageT(tsx1, t1l + tsrc, 64, t, 512);
    }
    stageT(bt0, qzTh + (size_t)b * 32768 + ii * 64, 512, t, 512);
    if (t < 64) {
      int ig = ii * 64 + t;
      float mi = (mask[b * 512 + ig] != 0) ? 1.f : 0.f;
      simi[t] = mi / sts[(b * 8 + c) * 512 + ig];
    }
    __syncthreads();
    if (diag) {
      A2_PASS(accU, true)
      __syncthreads();
      stageT(tsx0, t1h + tbb + ii * 4096 + KSTR, 64, t, 512);
      stageT(tsx1, t1l + tbb + ii * 4096 + KSTR, 64, t, 512);
      __syncthreads();
      A2_PASS(accL, false)
    } else if (kk0 == 0) {
      A2_PASS(accU, true)
    } else {
      A2_PASS(accL, false)
    }
  }
#pragma unroll
  for (int r = 0; r < 4; r++) {
    int row = jt * 64 + rg * 16 + g * 4 + r;
#pragma unroll
    for (int ntl = 0; ntl < 2; ntl++) {
      size_t o0 = ((size_t)b * 512 + row) * 1024 + c * 64 +
                  (nh * 2 + ntl) * 16 + cl;
      A2h[o0] = f2b(accU[ntl][r]);
      A2h[o0 + 512] = f2b(accL[ntl][r]);
    }
  }
}

// ---------------------------------------------------------------------------
// F{1,2} partials: Fp[part][b][m][n] = sum_{K part} A[b][m][K]·Tp[n][K]
// Plain bf16 GEMM (A and T hi-only — below existing noise floor).
// blk = sel*512 + part*64 + b*8 + it  (sel: 0->F1, 1->F2)
// ---------------------------------------------------------------------------
__global__ __launch_bounds__(256) void mm_fz_kernel(
    const u16* __restrict__ A1h, const u16* __restrict__ A2h,
    const u16* __restrict__ T1ph, const u16* __restrict__ T2ph,
    float* __restrict__ F1p, float* __restrict__ F2p) {
  int blk = blockIdx.x;
  int it = blk & 7, b = (blk >> 3) & 7, part = (blk >> 6) & 7, sel = blk >> 9;
  const u16* Ah = sel ? A2h : A1h;
  const u16* Bh = sel ? T2ph : T1ph;
  float* Fp = (sel ? F2p : F1p) + (size_t)part * (BB * 512 * 64);
  __shared__ u16 ah_s[4096], bh_s[4096];
  int t = threadIdx.x, lane = t & 63, w = t >> 6;
  f32x4 acc[4] = ACC_INIT;
  size_t abase = ((size_t)b * 512 + it * 64) * 1024;
  for (int cc2 = 0; cc2 < 2; cc2++) {
    int ch = part * 2 + cc2;
    __syncthreads();
    stageT(ah_s, Ah + abase + ch * 64, 1024, t, 256);
    stageT(bh_s, Bh + ch * 64, 1024, t, 256);
    __syncthreads();
    for (int ks = 0; ks < 2; ks++) {
      bf16x8 ah = frag64(ah_s, w * 16, ks, lane);
#pragma unroll
      for (int nt = 0; nt < 4; nt++)
        acc[nt] = MFMA(ah, frag64(bh_s, nt * 16, ks, lane), acc[nt]);
    }
  }
  int rb = (lane >> 4) * 4, cl = lane & 15;
#pragma unroll
  for (int nt = 0; nt < 4; nt++)
#pragma unroll
    for (int r = 0; r < 4; r++)
      Fp[((size_t)b * 512 + it * 64 + w * 16 + rb + r) * 64 + nt * 16 + cl] =
          acc[nt][r];
}

// ---------------------------------------------------------------------------
// fused q_g + F_Z (+ Z-softmax for non-final iters)
// ---------------------------------------------------------------------------
__global__ __launch_bounds__(256) void fzqg_kernel(
    const float* __restrict__ x, const float* __restrict__ F1p,
    const float* __restrict__ F2p, float* __restrict__ qz,
    u16* __restrict__ qzh, u16* __restrict__ qzl, const float* __restrict__ gw,
    const int* __restrict__ mask, float* __restrict__ out, int final_) {
  int blk = blockIdx.x;
  int ic = blk & 15, b = blk >> 4;
  int i0 = ic * 32;
  int t = threadIdx.x;
  __shared__ float gw_s[64][65];
  __shared__ float qz_s[32][64];
  __shared__ float fg_s[32][65];
  for (int p = t; p < 4096; p += 256) gw_s[p >> 6][p & 63] = gw[p];
  for (int p = t; p < 2048; p += 256) {
    int il = p >> 6, a = p & 63;
    qz_s[il][a] = qz[(b * LL + i0 + il) * 64 + a];
  }
  __syncthreads();
  int gcol = t & 63, il0 = t >> 6;
#pragma unroll
  for (int s = 0; s < 8; s++) {
    int il = il0 + 4 * s;
    float acc = 0.f;
    for (int a = 0; a < 64; a++) acc += qz_s[il][a] * gw_s[gcol][a];
    fg_s[il][gcol] = acc;
  }
  __syncthreads();
  {
    int r = t >> 3, k = t & 7;
    float v[8];
#pragma unroll
    for (int u = 0; u < 8; u++) v[u] = fg_s[r][k * 8 + u];
    float m = v[0];
#pragma unroll
    for (int u = 1; u < 8; u++) m = fmaxf(m, v[u]);
    for (int o = 1; o < 8; o <<= 1) m = fmaxf(m, __shfl_xor(m, o));
    float s = 0.f;
#pragma unroll
    for (int u = 0; u < 8; u++) s += __expf(v[u] - m);
    for (int o = 1; o < 8; o <<= 1) s += __shfl_xor(s, o);
    float mi = (mask[b * LL + i0 + r] != 0) ? 1.f : 0.f;
    float inv = mi / s;
#pragma unroll
    for (int u = 0; u < 8; u++) fg_s[r][k * 8 + u] = __expf(v[u] - m) * inv;
  }
  __syncthreads();
  int a = t & 63;
#pragma unroll
  for (int s = 0; s < 8; s++) {
    int il = il0 + 4 * s;
    float acc = 0.f;
    for (int g2 = 0; g2 < 64; g2++) acc += fg_s[il][g2] * gw_s[g2][a];
    size_t idx = (size_t)(b * LL + i0 + il) * 64 + a;
    float fs = x[idx] + acc;
    for (int p = 0; p < NP; p++)
      fs += F1p[(size_t)p * (BB * 512 * 64) + idx] +
            F2p[(size_t)p * (BB * 512 * 64) + idx];
    if (final_) {
      out[idx] = fs;
    } else {
      float m = fs;
      for (int o = 32; o; o >>= 1) m = fmaxf(m, __shfl_xor(m, o));
      float e = __expf(fs - m);
      float ss = e;
      for (int o = 32; o; o >>= 1) ss += __shfl_xor(ss, o);
      float mi = (mask[b * LL + i0 + il] != 0) ? 1.f : 0.f;
      float r = e / ss * mi;
      qz[idx] = r;
      u16 hi, lo;
      split2(r, hi, lo);
      qzh[idx] = hi;
      qzl[idx] = lo;
    }
  }
}

// ---------------------------------------------------------------------------
extern "C" void kernel_launch(void* const* d_in, const int* in_sizes, int n_in,
                              void* d_out, int out_size, void* d_ws,
                              size_t ws_size, hipStream_t stream) {
  const float* x = (const float*)d_in[0];
  const int* mask = (const int*)d_in[1];
  const float* ternary = (const float*)d_in[2];
  const float* gw = (const float*)d_in[3];
  float* out = (float*)d_out;

  char* w = (char*)d_ws;
  float* qz_f = (float*)(w);                           // 1 MB
  u16* qzh = (u16*)(w + (2 << 20));                    // 512 KB
  u16* qzl = (u16*)(w + (2 << 20) + (512 << 10));      // 512 KB
  u16* qzTh = (u16*)(w + (3 << 20));                   // 512 KB
  u16* qzTl = (u16*)(w + (3 << 20) + (512 << 10));     // 512 KB
  u16* TBh = (u16*)(w + (4 << 20));                    // 4 x 128 KB
  u16* TBl = (u16*)(w + (4 << 20) + (128 << 10));
  u16* T1ph = (u16*)(w + (4 << 20) + (256 << 10));
  u16* T2ph = (u16*)(w + (4 << 20) + (384 << 10));
  float* sts = (float*)(w + (5 << 20));                // 128 KB
  float* F1p = (float*)(w + (6 << 20));                // 8 MB
  float* F2p = (float*)(w + (14 << 20));               // 8 MB
  u16* t1h = (u16*)(w + (22 << 20));                   // 8 MB
  u16* t1l = (u16*)(w + (30 << 20));                   // 8 MB
  u16* A1h = (u16*)(w + (38 << 20));                   // 8 MB
  u16* A2h = (u16*)(w + (46 << 20));                   // 8 MB -> 54 MB total

  repack_kernel<<<256, 256, 0, stream>>>(ternary, TBh, TBl, T1ph, T2ph);
  softmax_z_kernel<<<BB * LL, 64, 0, stream>>>(x, mask, qz_f, qzh, qzl);
  for (int iter = 0; iter < NITER; iter++) {
    t1qzT_kernel<<<1152, 256, 0, stream>>>(qzh, qzl, TBh, TBl, t1h, t1l, qzTh,
                                           qzTl);
    a1_kernel<<<512, 512, 0, stream>>>(t1h, t1l, qzh, qzl, qzTh, mask, sts,
                                       A1h);
    a2_kernel<<<512, 512, 0, stream>>>(t1h, t1l, qzh, qzl, qzTh, sts, mask,
                                       A2h);
    mm_fz_kernel<<<1024, 256, 0, stream>>>(A1h, A2h, T1ph, T2ph, F1p, F2p);
    fzqg_kernel<<<128, 256, 0, stream>>>(x, F1p, F2p, qz_f, qzh, qzl, gw,
                                         mask, out, iter == NITER - 1);
  }
}

// Round 16
// 248.886 us; speedup vs baseline: 1.2952x; 1.1042x over previous
//
#include <hip/hip_runtime.h>
#include <hip/hip_bf16.h>

#define BB 8
#define LL 512
#define CC 8
#define NITER 3
#define NP 4  // split-K parts for mm_fz

typedef __attribute__((ext_vector_type(8))) short bf16x8;
typedef __attribute__((ext_vector_type(4))) float f32x4;
typedef unsigned short u16;

#define MFMA(A, B, C) __builtin_amdgcn_mfma_f32_16x16x32_bf16(A, B, C, 0, 0, 0)

__device__ inline u16 f2b(float f) {
  __hip_bfloat16 h = __float2bfloat16(f);
  return *reinterpret_cast<u16*>(&h);
}
__device__ inline float b2f(u16 u) {
  __hip_bfloat16 h;
  *reinterpret_cast<u16*>(&h) = u;
  return __bfloat162float(h);
}
__device__ inline void split2(float v, u16& hi, u16& lo) {
  hi = f2b(v);
  lo = f2b(v - b2f(hi));
}

// Stage a [64][64] bf16 tile (row stride ld) into LDS, XOR-swizzled.
__device__ inline void stageT(u16* lds, const u16* __restrict__ src, int ld,
                              int t, int nthr) {
  for (int ch = t; ch < 512; ch += nthr) {
    int r = ch >> 3, seg = ch & 7;
    int byte = (r * 128 + seg * 16) ^ ((r & 7) << 4);
    *(bf16x8*)((char*)lds + byte) = *(const bf16x8*)(src + r * ld + seg * 8);
  }
}
// mfma_16x16x32 operand fragment from swizzled tile: rows row0..row0+15.
__device__ inline bf16x8 frag64(const u16* lds, int row0, int ks, int lane) {
  int r = row0 + (lane & 15);
  int byte = (r * 128 + ks * 64 + ((lane >> 4) << 4)) ^ ((r & 7) << 4);
  return *(const bf16x8*)((const char*)lds + byte);
}
// split-precision accumulate: acc += Ah*Bh + Ah*Bl + Al*Bh
__device__ inline void mfma3(f32x4& acc, bf16x8 ah, bf16x8 al, bf16x8 bh,
                             bf16x8 bl) {
  acc = MFMA(ah, bh, acc);
  acc = MFMA(ah, bl, acc);
  acc = MFMA(al, bh, acc);
}

#define ACC_INIT {{0.f,0.f,0.f,0.f},{0.f,0.f,0.f,0.f},{0.f,0.f,0.f,0.f},{0.f,0.f,0.f,0.f}}

// ---------------------------------------------------------------------------
// repack ternary: TB split pairs (logit path), T1p/T2p hi-only (mm_fz path).
// ---------------------------------------------------------------------------
__global__ __launch_bounds__(256) void repack_kernel(
    const float* __restrict__ T, u16* TBh, u16* TBl, u16* T1h, u16* T2h) {
  int tid = blockIdx.x * 256 + threadIdx.x;  // [2][64][64][8]
  int c = tid & 7, e = (tid >> 3) & 63, a = (tid >> 9) & 63, kk = tid >> 15;
  u16 hi, lo;
  split2(T[tid], hi, lo);
  int iTB = ((kk * 8 + c) * 64 + e) * 64 + a;
  int i1 = a * 1024 + kk * 512 + c * 64 + e;
  int i2 = e * 1024 + kk * 512 + c * 64 + a;
  TBh[iTB] = hi;
  TBl[iTB] = lo;
  T1h[i1] = hi;
  T2h[i2] = hi;
}

// ---------------------------------------------------------------------------
// q_z = softmax(x) * m1 ; fp32 + split-bf16 copies  (iteration 0 only)
// ---------------------------------------------------------------------------
__global__ __launch_bounds__(64) void softmax_z_kernel(
    const float* __restrict__ in, const int* __restrict__ mask,
    float* __restrict__ qz, u16* __restrict__ qzh, u16* __restrict__ qzl) {
  int row = blockIdx.x;
  int t = threadIdx.x;
  float v = in[row * 64 + t];
  float m = v;
  for (int o = 32; o; o >>= 1) m = fmaxf(m, __shfl_xor(m, o));
  float e = __expf(v - m);
  float s = e;
  for (int o = 32; o; o >>= 1) s += __shfl_xor(s, o);
  float mi = (mask[row] != 0) ? 1.f : 0.f;
  float r = e / s * mi;
  qz[row * 64 + t] = r;
  u16 hi, lo;
  split2(r, hi, lo);
  qzh[row * 64 + t] = hi;
  qzl[row * 64 + t] = lo;
}

// ---------------------------------------------------------------------------
// fused: blk<1024 -> t1[kk,b,c][i][e] = sum_a qz[b,i,a]*T[kk,a,e,c]
//        blk>=1024 -> qzT[b][a][i] = qz[b][i][a]  (hi and lo)
// ---------------------------------------------------------------------------
__global__ __launch_bounds__(256) void t1qzT_kernel(
    const u16* __restrict__ qzh, const u16* __restrict__ qzl,
    const u16* __restrict__ TBh, const u16* __restrict__ TBl,
    u16* __restrict__ t1h, u16* __restrict__ t1l, u16* __restrict__ qzTh,
    u16* __restrict__ qzTl) {
  __shared__ u16 smem[16384];  // 32 KB, aliased by both paths
  int blk = blockIdx.x;
  int t = threadIdx.x;
  if (blk >= 1024) {
    int blk2 = blk - 1024;  // sel*64 + b*8 + it
    int it = blk2 & 7, b = (blk2 >> 3) & 7, sel = blk2 >> 6;
    const u16* src = sel ? qzl : qzh;
    u16* dst = sel ? qzTl : qzTh;
    u16(*s)[65] = (u16(*)[65])smem;
    for (int p = t; p < 4096; p += 256) {
      int r = p >> 6, a = p & 63;
      s[r][a] = src[(b * 512 + it * 64 + r) * 64 + a];
    }
    __syncthreads();
    for (int p = t; p < 4096; p += 256) {
      int a = p >> 6, i = p & 63;
      dst[(b * 64 + a) * 512 + it * 64 + i] = s[i][a];
    }
    return;
  }
  int it = blk & 7, c = (blk >> 3) & 7, b = (blk >> 6) & 7, kk = blk >> 9;
  u16* ah_s = smem;
  u16* al_s = smem + 4096;
  u16* bh_s = smem + 8192;
  u16* bl_s = smem + 12288;
  int lane = t & 63, w = t >> 6;
  stageT(ah_s, qzh + (b * 512 + it * 64) * 64, 64, t, 256);
  stageT(al_s, qzl + (b * 512 + it * 64) * 64, 64, t, 256);
  stageT(bh_s, TBh + (kk * 8 + c) * 4096, 64, t, 256);
  stageT(bl_s, TBl + (kk * 8 + c) * 4096, 64, t, 256);
  __syncthreads();
  f32x4 acc[4] = ACC_INIT;
  for (int ks = 0; ks < 2; ks++) {
    bf16x8 ah = frag64(ah_s, w * 16, ks, lane);
    bf16x8 al = frag64(al_s, w * 16, ks, lane);
#pragma unroll
    for (int nt = 0; nt < 4; nt++)
      mfma3(acc[nt], ah, al, frag64(bh_s, nt * 16, ks, lane),
            frag64(bl_s, nt * 16, ks, lane));
  }
  size_t base = ((size_t)((kk * 8 + b) * 8 + c)) * 32768;
  int rb = (lane >> 4) * 4, cl = lane & 15;
#pragma unroll
  for (int nt = 0; nt < 4; nt++)
#pragma unroll
    for (int r = 0; r < 4; r++) {
      size_t o = base + (size_t)(it * 64 + w * 16 + rb + r) * 64 + nt * 16 + cl;
      u16 h, l;
      split2(acc[nt][r], h, l);
      t1h[o] = h;
      t1l[o] = l;
    }
}

// ---------------------------------------------------------------------------
// a1: fused no-max softmax + A1 = (qh*dm) @ qz.  Writes sts (denominators).
// GEMM1: A = t1 split (regs), B = qz hi-only.  GEMM2 B hi-only, A1 hi-only.
// 512 threads: wave w -> row-group rg=w&3 (16 rows), col-half nh=w>>2.
// ---------------------------------------------------------------------------
#define A1_PASS(TFH, TFL, ACC, KKis0)                                        \
  {                                                                          \
    f32x4 accq0 = {0.f, 0.f, 0.f, 0.f}, accq1 = {0.f, 0.f, 0.f, 0.f};       \
    _Pragma("unroll") for (int ks = 0; ks < 2; ks++) {                       \
      bf16x8 bh0 = frag64(bx0, (nh * 2) * 16, ks, lane);                     \
      bf16x8 bh1 = frag64(bx0, (nh * 2 + 1) * 16, ks, lane);                 \
      accq0 = MFMA(TFH[ks], bh0, accq0);                                     \
      accq0 = MFMA(TFL[ks], bh0, accq0);                                     \
      accq1 = MFMA(TFH[ks], bh1, accq1);                                     \
      accq1 = MFMA(TFL[ks], bh1, accq1);                                     \
    }                                                                        \
    _Pragma("unroll") for (int ntl = 0; ntl < 2; ntl++) {                    \
      int col = (nh * 2 + ntl) * 16 + cl;                                    \
      int jg = jt * 64 + col;                                                \
      float mj = (mask[b * 512 + jg] != 0) ? 1.f : 0.f;                      \
      _Pragma("unroll") for (int r = 0; r < 4; r++) {                        \
        int row = rg * 16 + g * 4 + r;                                       \
        int ig = it * 64 + row;                                              \
        float e = __expf(ntl ? accq1[r] : accq0[r]);                         \
        float es, q;                                                         \
        if (KKis0) {                                                         \
          es = (jg > ig) ? e : ((jg == ig) ? 1.f : 0.f);                     \
          q = (jg > ig) ? e * mj : 0.f;                                      \
        } else {                                                             \
          es = (jg < ig) ? e : 0.f;                                          \
          q = (jg < ig) ? e * mj : 0.f;                                      \
        }                                                                    \
        s_run[r] += es;                                                      \
        int byte = (row * 128 + col * 2) ^ ((row & 7) << 4);                 \
        *(u16*)((char*)qh_s + byte) = f2b(q);                                \
      }                                                                      \
    }                                                                        \
    __syncthreads();                                                         \
    _Pragma("unroll") for (int ks = 0; ks < 2; ks++) {                       \
      bf16x8 ah = frag64(qh_s, rg * 16, ks, lane);                           \
      _Pragma("unroll") for (int ntl = 0; ntl < 2; ntl++) {                  \
        int nt = nh * 2 + ntl;                                               \
        bf16x8 bh = frag64(bt0, nt * 16, ks, lane);                          \
        ACC[ntl] = MFMA(ah, bh, ACC[ntl]);                                   \
      }                                                                      \
    }                                                                        \
  }

__global__ __launch_bounds__(512, 4) void a1_kernel(
    const u16* __restrict__ t1h, const u16* __restrict__ t1l,
    const u16* __restrict__ qzh, const u16* __restrict__ qzl,
    const u16* __restrict__ qzTh, const int* __restrict__ mask,
    float* __restrict__ sts, u16* __restrict__ A1h) {
  int blk = blockIdx.x;  // b*64 + c*8 + it
  int it = blk & 7, c = (blk >> 3) & 7, b = blk >> 6;
  __shared__ u16 smem[16640];  // 33280 B
  u16* bx0 = smem;             // qz[jt] hi
  u16* bx1 = smem + 4096;      // prologue temp only
  u16* bt0 = smem + 8192;      // qzT hi
  u16* qh_s = smem + 12288;    // qh hi
  float* ps = (float*)(smem + 16384);  // [2][64]
  int t = threadIdx.x, lane = t & 63, w = t >> 6, cl = lane & 15, g = lane >> 4;
  int rg = w & 3, nh = w >> 2;
  const size_t KSTR = (size_t)64 * 32768;
  size_t tb = ((size_t)(b * 8 + c)) * 32768 + it * 4096;
  // prologue: stage both t1 tiles (kk0 hi/lo, kk1 hi/lo), hoist A-frags
  stageT(bx0, t1h + tb, 64, t, 512);
  stageT(bx1, t1l + tb, 64, t, 512);
  stageT(bt0, t1h + tb + KSTR, 64, t, 512);
  stageT(qh_s, t1l + tb + KSTR, 64, t, 512);
  __syncthreads();
  bf16x8 tf0h[2], tf0l[2], tf1h[2], tf1l[2];
#pragma unroll
  for (int ks = 0; ks < 2; ks++) {
    tf0h[ks] = frag64(bx0, rg * 16, ks, lane);
    tf0l[ks] = frag64(bx1, rg * 16, ks, lane);
    tf1h[ks] = frag64(bt0, rg * 16, ks, lane);
    tf1l[ks] = frag64(qh_s, rg * 16, ks, lane);
  }
  float mi_[4], s_run[4];
#pragma unroll
  for (int r = 0; r < 4; r++) {
    mi_[r] = (mask[b * 512 + it * 64 + rg * 16 + g * 4 + r] != 0) ? 1.f : 0.f;
    s_run[r] = 0.f;
  }
  f32x4 accU[2] = {{0.f, 0.f, 0.f, 0.f}, {0.f, 0.f, 0.f, 0.f}};
  f32x4 accL[2] = {{0.f, 0.f, 0.f, 0.f}, {0.f, 0.f, 0.f, 0.f}};

#pragma unroll 1
  for (int jt = 0; jt < 8; jt++) {
    __syncthreads();  // protects hoist reads (jt=0) / prior GEMM reads
    stageT(bx0, qzh + (b * 512 + jt * 64) * 64, 64, t, 512);
    stageT(bt0, qzTh + (size_t)b * 32768 + jt * 64, 512, t, 512);
    __syncthreads();
    if (jt > it) {
      A1_PASS(tf0h, tf0l, accU, true)
    } else if (jt < it) {
      A1_PASS(tf1h, tf1l, accL, false)
    } else {
      A1_PASS(tf0h, tf0l, accU, true)
      __syncthreads();  // qh_s rewrite vs GEMM2 reads
      A1_PASS(tf1h, tf1l, accL, false)
    }
  }
  // epilogue: one reduction for s, then scale + store
#pragma unroll
  for (int r = 0; r < 4; r++) {
    float s = s_run[r];
    s += __shfl_xor(s, 1);
    s += __shfl_xor(s, 2);
    s += __shfl_xor(s, 4);
    s += __shfl_xor(s, 8);
    s_run[r] = s;
  }
  __syncthreads();
  if (cl == 0) {
#pragma unroll
    for (int r = 0; r < 4; r++) ps[nh * 64 + rg * 16 + g * 4 + r] = s_run[r];
  }
  __syncthreads();
#pragma unroll
  for (int r = 0; r < 4; r++) {
    int row = rg * 16 + g * 4 + r;
    float stot = ps[row] + ps[64 + row];
    float scale = mi_[r] / stot;
    int grow = it * 64 + row;
#pragma unroll
    for (int ntl = 0; ntl < 2; ntl++) {
      size_t o0 = ((size_t)b * 512 + grow) * 1024 + c * 64 +
                  (nh * 2 + ntl) * 16 + cl;
      A1h[o0] = f2b(accU[ntl][r] * scale);
      A1h[o0 + 512] = f2b(accL[ntl][r] * scale);
    }
    if (nh == 0 && cl == 0) sts[(b * 8 + c) * 512 + grow] = stot;
  }
}

// ---------------------------------------------------------------------------
// a2: A2[b][j][kk,c,a] = sum_i qh[kk][i][j]·qz[i][a]  (recompute, uses sts)
// GEMM1: A = qz split (regs), B = t1 hi-only.  GEMM2 B hi-only, A2 hi-only.
// ---------------------------------------------------------------------------
#define A2_PASS(ACC, KKis0)                                                  \
  {                                                                          \
    f32x4 accq0 = {0.f, 0.f, 0.f, 0.f}, accq1 = {0.f, 0.f, 0.f, 0.f};       \
    _Pragma("unroll") for (int ks = 0; ks < 2; ks++) {                       \
      bf16x8 bh0 = frag64(tsx0, (nh * 2) * 16, ks, lane);                    \
      bf16x8 bh1 = frag64(tsx0, (nh * 2 + 1) * 16, ks, lane);                \
      accq0 = MFMA(afh[ks], bh0, accq0);                                     \
      accq0 = MFMA(afl[ks], bh0, accq0);                                     \
      accq1 = MFMA(afh[ks], bh1, accq1);                                     \
      accq1 = MFMA(afl[ks], bh1, accq1);                                     \
    }                                                                        \
    _Pragma("unroll") for (int ntl = 0; ntl < 2; ntl++) {                    \
      int col = (nh * 2 + ntl) * 16 + cl;                                    \
      int ig = ii * 64 + col;                                                \
      float sim = simi[col];                                                 \
      _Pragma("unroll") for (int r = 0; r < 4; r++) {                        \
        int row = rg * 16 + g * 4 + r;                                       \
        int jg = jt * 64 + row;                                              \
        float e = __expf(ntl ? accq1[r] : accq0[r]);                         \
        bool keep = KKis0 ? (jg > ig) : (jg < ig);                           \
        float q = keep ? e * sim * mjrow[r] : 0.f;                           \
        int byte = (row * 128 + col * 2) ^ ((row & 7) << 4);                 \
        *(u16*)((char*)qh_s + byte) = f2b(q);                                \
      }                                                                      \
    }                                                                        \
    __syncthreads();                                                         \
    _Pragma("unroll") for (int ks = 0; ks < 2; ks++) {                       \
      bf16x8 ah = frag64(qh_s, rg * 16, ks, lane);                           \
      _Pragma("unroll") for (int ntl = 0; ntl < 2; ntl++) {                  \
        int nt = nh * 2 + ntl;                                               \
        bf16x8 bh = frag64(bt0, nt * 16, ks, lane);                          \
        ACC[ntl] = MFMA(ah, bh, ACC[ntl]);                                   \
      }                                                                      \
    }                                                                        \
  }

__global__ __launch_bounds__(512, 4) void a2_kernel(
    const u16* __restrict__ t1h, const u16* __restrict__ qzh,
    const u16* __restrict__ qzl, const u16* __restrict__ qzTh,
    const float* __restrict__ sts, const int* __restrict__ mask,
    u16* __restrict__ A2h) {
  int blk = blockIdx.x;  // b*64 + c*8 + jt
  int jt = blk & 7, c = (blk >> 3) & 7, b = blk >> 6;
  __shared__ u16 smem[16512];  // 33024 B
  u16* tsx0 = smem;            // t1 tile hi
  u16* tsx1 = smem + 4096;     // prologue temp only
  u16* bt0 = smem + 8192;      // qzT hi
  u16* qh_s = smem + 12288;    // qhT hi
  float* simi = (float*)(smem + 16384);  // [64] = mi/s per i
  int t = threadIdx.x, lane = t & 63, w = t >> 6, cl = lane & 15, g = lane >> 4;
  int rg = w & 3, nh = w >> 2;
  const size_t KSTR = (size_t)64 * 32768;
  size_t tbb = ((size_t)(b * 8 + c)) * 32768;
  // prologue: stage qz[jt] hi/lo, hoist A-frags
  stageT(tsx0, qzh + (b * 512 + jt * 64) * 64, 64, t, 512);
  stageT(tsx1, qzl + (b * 512 + jt * 64) * 64, 64, t, 512);
  __syncthreads();
  bf16x8 afh[2], afl[2];
#pragma unroll
  for (int ks = 0; ks < 2; ks++) {
    afh[ks] = frag64(tsx0, rg * 16, ks, lane);
    afl[ks] = frag64(tsx1, rg * 16, ks, lane);
  }
  float mjrow[4];
#pragma unroll
  for (int r = 0; r < 4; r++) {
    int jg = jt * 64 + rg * 16 + g * 4 + r;
    mjrow[r] = (mask[b * 512 + jg] != 0) ? 1.f : 0.f;
  }
  f32x4 accU[2] = {{0.f, 0.f, 0.f, 0.f}, {0.f, 0.f, 0.f, 0.f}};
  f32x4 accL[2] = {{0.f, 0.f, 0.f, 0.f}, {0.f, 0.f, 0.f, 0.f}};

#pragma unroll 1
  for (int ii = 0; ii < 8; ii++) {
    int diag = (ii == jt);
    int kk0 = (ii < jt) ? 0 : 1;
    __syncthreads();
    {
      size_t tsrc = tbb + ii * 4096 + ((diag || kk0 == 0) ? 0 : KSTR);
      stageT(tsx0, t1h + tsrc, 64, t, 512);
    }
    stageT(bt0, qzTh + (size_t)b * 32768 + ii * 64, 512, t, 512);
    if (t < 64) {
      int ig = ii * 64 + t;
      float mi = (mask[b * 512 + ig] != 0) ? 1.f : 0.f;
      simi[t] = mi / sts[(b * 8 + c) * 512 + ig];
    }
    __syncthreads();
    if (diag) {
      A2_PASS(accU, true)
      __syncthreads();
      stageT(tsx0, t1h + tbb + ii * 4096 + KSTR, 64, t, 512);
      __syncthreads();
      A2_PASS(accL, false)
    } else if (kk0 == 0) {
      A2_PASS(accU, true)
    } else {
      A2_PASS(accL, false)
    }
  }
#pragma unroll
  for (int r = 0; r < 4; r++) {
    int row = jt * 64 + rg * 16 + g * 4 + r;
#pragma unroll
    for (int ntl = 0; ntl < 2; ntl++) {
      size_t o0 = ((size_t)b * 512 + row) * 1024 + c * 64 +
                  (nh * 2 + ntl) * 16 + cl;
      A2h[o0] = f2b(accU[ntl][r]);
      A2h[o0 + 512] = f2b(accL[ntl][r]);
    }
  }
}

// ---------------------------------------------------------------------------
// F{1,2} partials: Fp[part][b][m][n] = sum_{K part} A[b][m][K]·Tp[n][K]
// Plain bf16 GEMM.  blk = sel*256 + part*64 + b*8 + it  (sel: 0->F1, 1->F2)
// ---------------------------------------------------------------------------
__global__ __launch_bounds__(256) void mm_fz_kernel(
    const u16* __restrict__ A1h, const u16* __restrict__ A2h,
    const u16* __restrict__ T1ph, const u16* __restrict__ T2ph,
    float* __restrict__ F1p, float* __restrict__ F2p) {
  int blk = blockIdx.x;
  int it = blk & 7, b = (blk >> 3) & 7, part = (blk >> 6) & 3, sel = blk >> 8;
  const u16* Ah = sel ? A2h : A1h;
  const u16* Bh = sel ? T2ph : T1ph;
  float* Fp = (sel ? F2p : F1p) + (size_t)part * (BB * 512 * 64);
  __shared__ u16 ah_s[4096], bh_s[4096];
  int t = threadIdx.x, lane = t & 63, w = t >> 6;
  f32x4 acc[4] = ACC_INIT;
  size_t abase = ((size_t)b * 512 + it * 64) * 1024;
  for (int cc2 = 0; cc2 < 4; cc2++) {
    int ch = part * 4 + cc2;
    __syncthreads();
    stageT(ah_s, Ah + abase + ch * 64, 1024, t, 256);
    stageT(bh_s, Bh + ch * 64, 1024, t, 256);
    __syncthreads();
    for (int ks = 0; ks < 2; ks++) {
      bf16x8 ah = frag64(ah_s, w * 16, ks, lane);
#pragma unroll
      for (int nt = 0; nt < 4; nt++)
        acc[nt] = MFMA(ah, frag64(bh_s, nt * 16, ks, lane), acc[nt]);
    }
  }
  int rb = (lane >> 4) * 4, cl = lane & 15;
#pragma unroll
  for (int nt = 0; nt < 4; nt++)
#pragma unroll
    for (int r = 0; r < 4; r++)
      Fp[((size_t)b * 512 + it * 64 + w * 16 + rb + r) * 64 + nt * 16 + cl] =
          acc[nt][r];
}

// ---------------------------------------------------------------------------
// fused q_g + F_Z (+ Z-softmax for non-final iters)
// ---------------------------------------------------------------------------
__global__ __launch_bounds__(256) void fzqg_kernel(
    const float* __restrict__ x, const float* __restrict__ F1p,
    const float* __restrict__ F2p, float* __restrict__ qz,
    u16* __restrict__ qzh, u16* __restrict__ qzl, const float* __restrict__ gw,
    const int* __restrict__ mask, float* __restrict__ out, int final_) {
  int blk = blockIdx.x;
  int ic = blk & 15, b = blk >> 4;
  int i0 = ic * 32;
  int t = threadIdx.x;
  __shared__ float gw_s[64][65];
  __shared__ float qz_s[32][64];
  __shared__ float fg_s[32][65];
  for (int p = t; p < 4096; p += 256) gw_s[p >> 6][p & 63] = gw[p];
  for (int p = t; p < 2048; p += 256) {
    int il = p >> 6, a = p & 63;
    qz_s[il][a] = qz[(b * LL + i0 + il) * 64 + a];
  }
  __syncthreads();
  int gcol = t & 63, il0 = t >> 6;
#pragma unroll
  for (int s = 0; s < 8; s++) {
    int il = il0 + 4 * s;
    float acc = 0.f;
    for (int a = 0; a < 64; a++) acc += qz_s[il][a] * gw_s[gcol][a];
    fg_s[il][gcol] = acc;
  }
  __syncthreads();
  {
    int r = t >> 3, k = t & 7;
    float v[8];
#pragma unroll
    for (int u = 0; u < 8; u++) v[u] = fg_s[r][k * 8 + u];
    float m = v[0];
#pragma unroll
    for (int u = 1; u < 8; u++) m = fmaxf(m, v[u]);
    for (int o = 1; o < 8; o <<= 1) m = fmaxf(m, __shfl_xor(m, o));
    float s = 0.f;
#pragma unroll
    for (int u = 0; u < 8; u++) s += __expf(v[u] - m);
    for (int o = 1; o < 8; o <<= 1) s += __shfl_xor(s, o);
    float mi = (mask[b * LL + i0 + r] != 0) ? 1.f : 0.f;
    float inv = mi / s;
#pragma unroll
    for (int u = 0; u < 8; u++) fg_s[r][k * 8 + u] = __expf(v[u] - m) * inv;
  }
  __syncthreads();
  int a = t & 63;
#pragma unroll
  for (int s = 0; s < 8; s++) {
    int il = il0 + 4 * s;
    float acc = 0.f;
    for (int g2 = 0; g2 < 64; g2++) acc += fg_s[il][g2] * gw_s[g2][a];
    size_t idx = (size_t)(b * LL + i0 + il) * 64 + a;
    float fs = x[idx] + acc;
    for (int p = 0; p < NP; p++)
      fs += F1p[(size_t)p * (BB * 512 * 64) + idx] +
            F2p[(size_t)p * (BB * 512 * 64) + idx];
    if (final_) {
      out[idx] = fs;
    } else {
      float m = fs;
      for (int o = 32; o; o >>= 1) m = fmaxf(m, __shfl_xor(m, o));
      float e = __expf(fs - m);
      float ss = e;
      for (int o = 32; o; o >>= 1) ss += __shfl_xor(ss, o);
      float mi = (mask[b * LL + i0 + il] != 0) ? 1.f : 0.f;
      float r = e / ss * mi;
      qz[idx] = r;
      u16 hi, lo;
      split2(r, hi, lo);
      qzh[idx] = hi;
      qzl[idx] = lo;
    }
  }
}

// ---------------------------------------------------------------------------
extern "C" void kernel_launch(void* const* d_in, const int* in_sizes, int n_in,
                              void* d_out, int out_size, void* d_ws,
                              size_t ws_size, hipStream_t stream) {
  const float* x = (const float*)d_in[0];
  const int* mask = (const int*)d_in[1];
  const float* ternary = (const float*)d_in[2];
  const float* gw = (const float*)d_in[3];
  float* out = (float*)d_out;

  char* w = (char*)d_ws;
  float* qz_f = (float*)(w);                           // 1 MB
  u16* qzh = (u16*)(w + (2 << 20));                    // 512 KB
  u16* qzl = (u16*)(w + (2 << 20) + (512 << 10));      // 512 KB
  u16* qzTh = (u16*)(w + (3 << 20));                   // 512 KB
  u16* qzTl = (u16*)(w + (3 << 20) + (512 << 10));     // 512 KB
  u16* TBh = (u16*)(w + (4 << 20));                    // 4 x 128 KB
  u16* TBl = (u16*)(w + (4 << 20) + (128 << 10));
  u16* T1ph = (u16*)(w + (4 << 20) + (256 << 10));
  u16* T2ph = (u16*)(w + (4 << 20) + (384 << 10));
  float* sts = (float*)(w + (5 << 20));                // 128 KB
  float* F1p = (float*)(w + (6 << 20));                // 4 MB (NP=4)
  float* F2p = (float*)(w + (14 << 20));               // 4 MB
  u16* t1h = (u16*)(w + (22 << 20));                   // 8 MB
  u16* t1l = (u16*)(w + (30 << 20));                   // 8 MB
  u16* A1h = (u16*)(w + (38 << 20));                   // 8 MB
  u16* A2h = (u16*)(w + (46 << 20));                   // 8 MB -> 54 MB total

  repack_kernel<<<256, 256, 0, stream>>>(ternary, TBh, TBl, T1ph, T2ph);
  softmax_z_kernel<<<BB * LL, 64, 0, stream>>>(x, mask, qz_f, qzh, qzl);
  for (int iter = 0; iter < NITER; iter++) {
    t1qzT_kernel<<<1152, 256, 0, stream>>>(qzh, qzl, TBh, TBl, t1h, t1l, qzTh,
                                           qzTl);
    a1_kernel<<<512, 512, 0, stream>>>(t1h, t1l, qzh, qzl, qzTh, mask, sts,
                                       A1h);
    a2_kernel<<<512, 512, 0, stream>>>(t1h, qzh, qzl, qzTh, sts, mask, A2h);
    mm_fz_kernel<<<512, 256, 0, stream>>>(A1h, A2h, T1ph, T2ph, F1p, F2p);
    fzqg_kernel<<<128, 256, 0, stream>>>(x, F1p, F2p, qz_f, qzh, qzl, gw,
                                         mask, out, iter == NITER - 1);
  }
}

// Round 17
// 238.636 us; speedup vs baseline: 1.3509x; 1.0430x over previous
//
#include <hip/hip_runtime.h>
#include <hip/hip_bf16.h>

#define BB 8
#define LL 512
#define CC 8
#define NITER 3
#define NP 4  // split-K parts for mm_fz

typedef __attribute__((ext_vector_type(8))) short bf16x8;
typedef __attribute__((ext_vector_type(4))) float f32x4;
typedef unsigned short u16;

#define MFMA(A, B, C) __builtin_amdgcn_mfma_f32_16x16x32_bf16(A, B, C, 0, 0, 0)

__device__ inline u16 f2b(float f) {
  __hip_bfloat16 h = __float2bfloat16(f);
  return *reinterpret_cast<u16*>(&h);
}
__device__ inline float b2f(u16 u) {
  __hip_bfloat16 h;
  *reinterpret_cast<u16*>(&h) = u;
  return __bfloat162float(h);
}
__device__ inline void split2(float v, u16& hi, u16& lo) {
  hi = f2b(v);
  lo = f2b(v - b2f(hi));
}

// Stage a [64][64] bf16 tile (row stride ld) into LDS, XOR-swizzled.
__device__ inline void stageT(u16* lds, const u16* __restrict__ src, int ld,
                              int t, int nthr) {
  for (int ch = t; ch < 512; ch += nthr) {
    int r = ch >> 3, seg = ch & 7;
    int byte = (r * 128 + seg * 16) ^ ((r & 7) << 4);
    *(bf16x8*)((char*)lds + byte) = *(const bf16x8*)(src + r * ld + seg * 8);
  }
}
// mfma_16x16x32 operand fragment from swizzled tile: rows row0..row0+15.
__device__ inline bf16x8 frag64(const u16* lds, int row0, int ks, int lane) {
  int r = row0 + (lane & 15);
  int byte = (r * 128 + ks * 64 + ((lane >> 4) << 4)) ^ ((r & 7) << 4);
  return *(const bf16x8*)((const char*)lds + byte);
}
// split-precision accumulate: acc += Ah*Bh + Ah*Bl + Al*Bh
__device__ inline void mfma3(f32x4& acc, bf16x8 ah, bf16x8 al, bf16x8 bh,
                             bf16x8 bl) {
  acc = MFMA(ah, bh, acc);
  acc = MFMA(ah, bl, acc);
  acc = MFMA(al, bh, acc);
}

#define ACC_INIT {{0.f,0.f,0.f,0.f},{0.f,0.f,0.f,0.f},{0.f,0.f,0.f,0.f},{0.f,0.f,0.f,0.f}}

// ---------------------------------------------------------------------------
// repack ternary: TB split pairs (t1 GEMM), T1p/T2p hi-only (mm_fz path).
// ---------------------------------------------------------------------------
__global__ __launch_bounds__(256) void repack_kernel(
    const float* __restrict__ T, u16* TBh, u16* TBl, u16* T1h, u16* T2h) {
  int tid = blockIdx.x * 256 + threadIdx.x;  // [2][64][64][8]
  int c = tid & 7, e = (tid >> 3) & 63, a = (tid >> 9) & 63, kk = tid >> 15;
  u16 hi, lo;
  split2(T[tid], hi, lo);
  int iTB = ((kk * 8 + c) * 64 + e) * 64 + a;
  int i1 = a * 1024 + kk * 512 + c * 64 + e;
  int i2 = e * 1024 + kk * 512 + c * 64 + a;
  TBh[iTB] = hi;
  TBl[iTB] = lo;
  T1h[i1] = hi;
  T2h[i2] = hi;
}

// ---------------------------------------------------------------------------
// q_z = softmax(x) * m1 ; fp32 + split-bf16 copies  (iteration 0 only)
// (qzl feeds only the t1 split-GEMM.)
// ---------------------------------------------------------------------------
__global__ __launch_bounds__(64) void softmax_z_kernel(
    const float* __restrict__ in, const int* __restrict__ mask,
    float* __restrict__ qz, u16* __restrict__ qzh, u16* __restrict__ qzl) {
  int row = blockIdx.x;
  int t = threadIdx.x;
  float v = in[row * 64 + t];
  float m = v;
  for (int o = 32; o; o >>= 1) m = fmaxf(m, __shfl_xor(m, o));
  float e = __expf(v - m);
  float s = e;
  for (int o = 32; o; o >>= 1) s += __shfl_xor(s, o);
  float mi = (mask[row] != 0) ? 1.f : 0.f;
  float r = e / s * mi;
  qz[row * 64 + t] = r;
  u16 hi, lo;
  split2(r, hi, lo);
  qzh[row * 64 + t] = hi;
  qzl[row * 64 + t] = lo;
}

// ---------------------------------------------------------------------------
// fused: blk<1024 -> t1[kk,b,c][i][e] = sum_a qz[b,i,a]*T[kk,a,e,c] (hi out)
//        blk>=1024 -> qzTh[b][a][i] = qzh[b][i][a]
// ---------------------------------------------------------------------------
__global__ __launch_bounds__(256) void t1qzT_kernel(
    const u16* __restrict__ qzh, const u16* __restrict__ qzl,
    const u16* __restrict__ TBh, const u16* __restrict__ TBl,
    u16* __restrict__ t1h, u16* __restrict__ qzTh) {
  __shared__ u16 smem[16384];  // 32 KB, aliased by both paths
  int blk = blockIdx.x;
  int t = threadIdx.x;
  if (blk >= 1024) {
    int blk2 = blk - 1024;  // b*8 + it
    int it = blk2 & 7, b = blk2 >> 3;
    u16(*s)[65] = (u16(*)[65])smem;
    for (int p = t; p < 4096; p += 256) {
      int r = p >> 6, a = p & 63;
      s[r][a] = qzh[(b * 512 + it * 64 + r) * 64 + a];
    }
    __syncthreads();
    for (int p = t; p < 4096; p += 256) {
      int a = p >> 6, i = p & 63;
      qzTh[(b * 64 + a) * 512 + it * 64 + i] = s[i][a];
    }
    return;
  }
  int it = blk & 7, c = (blk >> 3) & 7, b = (blk >> 6) & 7, kk = blk >> 9;
  u16* ah_s = smem;
  u16* al_s = smem + 4096;
  u16* bh_s = smem + 8192;
  u16* bl_s = smem + 12288;
  int lane = t & 63, w = t >> 6;
  stageT(ah_s, qzh + (b * 512 + it * 64) * 64, 64, t, 256);
  stageT(al_s, qzl + (b * 512 + it * 64) * 64, 64, t, 256);
  stageT(bh_s, TBh + (kk * 8 + c) * 4096, 64, t, 256);
  stageT(bl_s, TBl + (kk * 8 + c) * 4096, 64, t, 256);
  __syncthreads();
  f32x4 acc[4] = ACC_INIT;
  for (int ks = 0; ks < 2; ks++) {
    bf16x8 ah = frag64(ah_s, w * 16, ks, lane);
    bf16x8 al = frag64(al_s, w * 16, ks, lane);
#pragma unroll
    for (int nt = 0; nt < 4; nt++)
      mfma3(acc[nt], ah, al, frag64(bh_s, nt * 16, ks, lane),
            frag64(bl_s, nt * 16, ks, lane));
  }
  size_t base = ((size_t)((kk * 8 + b) * 8 + c)) * 32768;
  int rb = (lane >> 4) * 4, cl = lane & 15;
#pragma unroll
  for (int nt = 0; nt < 4; nt++)
#pragma unroll
    for (int r = 0; r < 4; r++) {
      size_t o = base + (size_t)(it * 64 + w * 16 + rb + r) * 64 + nt * 16 + cl;
      t1h[o] = f2b(acc[nt][r]);
    }
}

// ---------------------------------------------------------------------------
// a1: fused no-max softmax + A1 = (qh*dm) @ qz.  Writes sts (denominators).
// All GEMM operands bf16 (hi-only).  512 threads: wave w -> rows rg=w&3,
// col-half nh=w>>2.
// ---------------------------------------------------------------------------
#define A1_PASS(TFH, ACC, KKis0)                                             \
  {                                                                          \
    f32x4 accq0 = {0.f, 0.f, 0.f, 0.f}, accq1 = {0.f, 0.f, 0.f, 0.f};       \
    _Pragma("unroll") for (int ks = 0; ks < 2; ks++) {                       \
      bf16x8 bh0 = frag64(bx0, (nh * 2) * 16, ks, lane);                     \
      bf16x8 bh1 = frag64(bx0, (nh * 2 + 1) * 16, ks, lane);                 \
      accq0 = MFMA(TFH[ks], bh0, accq0);                                     \
      accq1 = MFMA(TFH[ks], bh1, accq1);                                     \
    }                                                                        \
    _Pragma("unroll") for (int ntl = 0; ntl < 2; ntl++) {                    \
      int col = (nh * 2 + ntl) * 16 + cl;                                    \
      int jg = jt * 64 + col;                                                \
      float mj = (mask[b * 512 + jg] != 0) ? 1.f : 0.f;                      \
      _Pragma("unroll") for (int r = 0; r < 4; r++) {                        \
        int row = rg * 16 + g * 4 + r;                                       \
        int ig = it * 64 + row;                                              \
        float e = __expf(ntl ? accq1[r] : accq0[r]);                         \
        float es, q;                                                         \
        if (KKis0) {                                                         \
          es = (jg > ig) ? e : ((jg == ig) ? 1.f : 0.f);                     \
          q = (jg > ig) ? e * mj : 0.f;                                      \
        } else {                                                             \
          es = (jg < ig) ? e : 0.f;                                          \
          q = (jg < ig) ? e * mj : 0.f;                                      \
        }                                                                    \
        s_run[r] += es;                                                      \
        int byte = (row * 128 + col * 2) ^ ((row & 7) << 4);                 \
        *(u16*)((char*)qh_s + byte) = f2b(q);                                \
      }                                                                      \
    }                                                                        \
    __syncthreads();                                                         \
    _Pragma("unroll") for (int ks = 0; ks < 2; ks++) {                       \
      bf16x8 ah = frag64(qh_s, rg * 16, ks, lane);                           \
      _Pragma("unroll") for (int ntl = 0; ntl < 2; ntl++) {                  \
        int nt = nh * 2 + ntl;                                               \
        bf16x8 bh = frag64(bt0, nt * 16, ks, lane);                          \
        ACC[ntl] = MFMA(ah, bh, ACC[ntl]);                                   \
      }                                                                      \
    }                                                                        \
  }

__global__ __launch_bounds__(512, 4) void a1_kernel(
    const u16* __restrict__ t1h, const u16* __restrict__ qzh,
    const u16* __restrict__ qzTh, const int* __restrict__ mask,
    float* __restrict__ sts, u16* __restrict__ A1h) {
  int blk = blockIdx.x;  // b*64 + c*8 + it
  int it = blk & 7, c = (blk >> 3) & 7, b = blk >> 6;
  __shared__ u16 smem[12544];  // 25088 B
  u16* bx0 = smem;             // qz[jt] hi
  u16* bt0 = smem + 4096;      // qzT hi
  u16* qh_s = smem + 8192;     // qh hi
  float* ps = (float*)(smem + 12288);  // [2][64]
  int t = threadIdx.x, lane = t & 63, w = t >> 6, cl = lane & 15, g = lane >> 4;
  int rg = w & 3, nh = w >> 2;
  const size_t KSTR = (size_t)64 * 32768;
  size_t tb = ((size_t)(b * 8 + c)) * 32768 + it * 4096;
  // prologue: stage both t1 tiles, hoist A-frags
  stageT(bx0, t1h + tb, 64, t, 512);
  stageT(bt0, t1h + tb + KSTR, 64, t, 512);
  __syncthreads();
  bf16x8 tf0h[2], tf1h[2];
#pragma unroll
  for (int ks = 0; ks < 2; ks++) {
    tf0h[ks] = frag64(bx0, rg * 16, ks, lane);
    tf1h[ks] = frag64(bt0, rg * 16, ks, lane);
  }
  float mi_[4], s_run[4];
#pragma unroll
  for (int r = 0; r < 4; r++) {
    mi_[r] = (mask[b * 512 + it * 64 + rg * 16 + g * 4 + r] != 0) ? 1.f : 0.f;
    s_run[r] = 0.f;
  }
  f32x4 accU[2] = {{0.f, 0.f, 0.f, 0.f}, {0.f, 0.f, 0.f, 0.f}};
  f32x4 accL[2] = {{0.f, 0.f, 0.f, 0.f}, {0.f, 0.f, 0.f, 0.f}};

#pragma unroll 1
  for (int jt = 0; jt < 8; jt++) {
    __syncthreads();  // protects hoist reads (jt=0) / prior GEMM reads
    stageT(bx0, qzh + (b * 512 + jt * 64) * 64, 64, t, 512);
    stageT(bt0, qzTh + (size_t)b * 32768 + jt * 64, 512, t, 512);
    __syncthreads();
    if (jt > it) {
      A1_PASS(tf0h, accU, true)
    } else if (jt < it) {
      A1_PASS(tf1h, accL, false)
    } else {
      A1_PASS(tf0h, accU, true)
      __syncthreads();  // qh_s rewrite vs GEMM2 reads
      A1_PASS(tf1h, accL, false)
    }
  }
  // epilogue: one reduction for s, then scale + store
#pragma unroll
  for (int r = 0; r < 4; r++) {
    float s = s_run[r];
    s += __shfl_xor(s, 1);
    s += __shfl_xor(s, 2);
    s += __shfl_xor(s, 4);
    s += __shfl_xor(s, 8);
    s_run[r] = s;
  }
  __syncthreads();
  if (cl == 0) {
#pragma unroll
    for (int r = 0; r < 4; r++) ps[nh * 64 + rg * 16 + g * 4 + r] = s_run[r];
  }
  __syncthreads();
#pragma unroll
  for (int r = 0; r < 4; r++) {
    int row = rg * 16 + g * 4 + r;
    float stot = ps[row] + ps[64 + row];
    float scale = mi_[r] / stot;
    int grow = it * 64 + row;
#pragma unroll
    for (int ntl = 0; ntl < 2; ntl++) {
      size_t o0 = ((size_t)b * 512 + grow) * 1024 + c * 64 +
                  (nh * 2 + ntl) * 16 + cl;
      A1h[o0] = f2b(accU[ntl][r] * scale);
      A1h[o0 + 512] = f2b(accL[ntl][r] * scale);
    }
    if (nh == 0 && cl == 0) sts[(b * 8 + c) * 512 + grow] = stot;
  }
}

// ---------------------------------------------------------------------------
// a2: A2[b][j][kk,c,a] = sum_i qh[kk][i][j]·qz[i][a]  (recompute, uses sts)
// All GEMM operands bf16 (hi-only).
// ---------------------------------------------------------------------------
#define A2_PASS(ACC, KKis0)                                                  \
  {                                                                          \
    f32x4 accq0 = {0.f, 0.f, 0.f, 0.f}, accq1 = {0.f, 0.f, 0.f, 0.f};       \
    _Pragma("unroll") for (int ks = 0; ks < 2; ks++) {                       \
      bf16x8 bh0 = frag64(tsx0, (nh * 2) * 16, ks, lane);                    \
      bf16x8 bh1 = frag64(tsx0, (nh * 2 + 1) * 16, ks, lane);                \
      accq0 = MFMA(afh[ks], bh0, accq0);                                     \
      accq1 = MFMA(afh[ks], bh1, accq1);                                     \
    }                                                                        \
    _Pragma("unroll") for (int ntl = 0; ntl < 2; ntl++) {                    \
      int col = (nh * 2 + ntl) * 16 + cl;                                    \
      int ig = ii * 64 + col;                                                \
      float sim = simi[col];                                                 \
      _Pragma("unroll") for (int r = 0; r < 4; r++) {                        \
        int row = rg * 16 + g * 4 + r;                                       \
        int jg = jt * 64 + row;                                              \
        float e = __expf(ntl ? accq1[r] : accq0[r]);                         \
        bool keep = KKis0 ? (jg > ig) : (jg < ig);                           \
        float q = keep ? e * sim * mjrow[r] : 0.f;                           \
        int byte = (row * 128 + col * 2) ^ ((row & 7) << 4);                 \
        *(u16*)((char*)qh_s + byte) = f2b(q);                                \
      }                                                                      \
    }                                                                        \
    __syncthreads();                                                         \
    _Pragma("unroll") for (int ks = 0; ks < 2; ks++) {                       \
      bf16x8 ah = frag64(qh_s, rg * 16, ks, lane);                           \
      _Pragma("unroll") for (int ntl = 0; ntl < 2; ntl++) {                  \
        int nt = nh * 2 + ntl;                                               \
        bf16x8 bh = frag64(bt0, nt * 16, ks, lane);                          \
        ACC[ntl] = MFMA(ah, bh, ACC[ntl]);                                   \
      }                                                                      \
    }                                                                        \
  }

__global__ __launch_bounds__(512, 4) void a2_kernel(
    const u16* __restrict__ t1h, const u16* __restrict__ qzh,
    const u16* __restrict__ qzTh, const float* __restrict__ sts,
    const int* __restrict__ mask, u16* __restrict__ A2h) {
  int blk = blockIdx.x;  // b*64 + c*8 + jt
  int jt = blk & 7, c = (blk >> 3) & 7, b = blk >> 6;
  __shared__ u16 smem[12416];  // 24832 B
  u16* tsx0 = smem;            // t1 tile hi
  u16* bt0 = smem + 4096;      // qzT hi
  u16* qh_s = smem + 8192;     // qhT hi
  float* simi = (float*)(smem + 12288);  // [64] = mi/s per i
  int t = threadIdx.x, lane = t & 63, w = t >> 6, cl = lane & 15, g = lane >> 4;
  int rg = w & 3, nh = w >> 2;
  const size_t KSTR = (size_t)64 * 32768;
  size_t tbb = ((size_t)(b * 8 + c)) * 32768;
  // prologue: stage qz[jt] hi, hoist A-frags
  stageT(tsx0, qzh + (b * 512 + jt * 64) * 64, 64, t, 512);
  __syncthreads();
  bf16x8 afh[2];
#pragma unroll
  for (int ks = 0; ks < 2; ks++) afh[ks] = frag64(tsx0, rg * 16, ks, lane);
  float mjrow[4];
#pragma unroll
  for (int r = 0; r < 4; r++) {
    int jg = jt * 64 + rg * 16 + g * 4 + r;
    mjrow[r] = (mask[b * 512 + jg] != 0) ? 1.f : 0.f;
  }
  f32x4 accU[2] = {{0.f, 0.f, 0.f, 0.f}, {0.f, 0.f, 0.f, 0.f}};
  f32x4 accL[2] = {{0.f, 0.f, 0.f, 0.f}, {0.f, 0.f, 0.f, 0.f}};

#pragma unroll 1
  for (int ii = 0; ii < 8; ii++) {
    int diag = (ii == jt);
    int kk0 = (ii < jt) ? 0 : 1;
    __syncthreads();
    {
      size_t tsrc = tbb + ii * 4096 + ((diag || kk0 == 0) ? 0 : KSTR);
      stageT(tsx0, t1h + tsrc, 64, t, 512);
    }
    stageT(bt0, qzTh + (size_t)b * 32768 + ii * 64, 512, t, 512);
    if (t < 64) {
      int ig = ii * 64 + t;
      float mi = (mask[b * 512 + ig] != 0) ? 1.f : 0.f;
      simi[t] = mi / sts[(b * 8 + c) * 512 + ig];
    }
    __syncthreads();
    if (diag) {
      A2_PASS(accU, true)
      __syncthreads();
      stageT(tsx0, t1h + tbb + ii * 4096 + KSTR, 64, t, 512);
      __syncthreads();
      A2_PASS(accL, false)
    } else if (kk0 == 0) {
      A2_PASS(accU, true)
    } else {
      A2_PASS(accL, false)
    }
  }
#pragma unroll
  for (int r = 0; r < 4; r++) {
    int row = jt * 64 + rg * 16 + g * 4 + r;
#pragma unroll
    for (int ntl = 0; ntl < 2; ntl++) {
      size_t o0 = ((size_t)b * 512 + row) * 1024 + c * 64 +
                  (nh * 2 + ntl) * 16 + cl;
      A2h[o0] = f2b(accU[ntl][r]);
      A2h[o0 + 512] = f2b(accL[ntl][r]);
    }
  }
}

// ---------------------------------------------------------------------------
// F{1,2} partials: Fp[part][b][m][n] = sum_{K part} A[b][m][K]·Tp[n][K]
// Plain bf16 GEMM.  blk = sel*256 + part*64 + b*8 + it  (sel: 0->F1, 1->F2)
// ---------------------------------------------------------------------------
__global__ __launch_bounds__(256) void mm_fz_kernel(
    const u16* __restrict__ A1h, const u16* __restrict__ A2h,
    const u16* __restrict__ T1ph, const u16* __restrict__ T2ph,
    float* __restrict__ F1p, float* __restrict__ F2p) {
  int blk = blockIdx.x;
  int it = blk & 7, b = (blk >> 3) & 7, part = (blk >> 6) & 3, sel = blk >> 8;
  const u16* Ah = sel ? A2h : A1h;
  const u16* Bh = sel ? T2ph : T1ph;
  float* Fp = (sel ? F2p : F1p) + (size_t)part * (BB * 512 * 64);
  __shared__ u16 ah_s[4096], bh_s[4096];
  int t = threadIdx.x, lane = t & 63, w = t >> 6;
  f32x4 acc[4] = ACC_INIT;
  size_t abase = ((size_t)b * 512 + it * 64) * 1024;
  for (int cc2 = 0; cc2 < 4; cc2++) {
    int ch = part * 4 + cc2;
    __syncthreads();
    stageT(ah_s, Ah + abase + ch * 64, 1024, t, 256);
    stageT(bh_s, Bh + ch * 64, 1024, t, 256);
    __syncthreads();
    for (int ks = 0; ks < 2; ks++) {
      bf16x8 ah = frag64(ah_s, w * 16, ks, lane);
#pragma unroll
      for (int nt = 0; nt < 4; nt++)
        acc[nt] = MFMA(ah, frag64(bh_s, nt * 16, ks, lane), acc[nt]);
    }
  }
  int rb = (lane >> 4) * 4, cl = lane & 15;
#pragma unroll
  for (int nt = 0; nt < 4; nt++)
#pragma unroll
    for (int r = 0; r < 4; r++)
      Fp[((size_t)b * 512 + it * 64 + w * 16 + rb + r) * 64 + nt * 16 + cl] =
          acc[nt][r];
}

// ---------------------------------------------------------------------------
// fused q_g + F_Z (+ Z-softmax for non-final iters)
// ---------------------------------------------------------------------------
__global__ __launch_bounds__(256) void fzqg_kernel(
    const float* __restrict__ x, const float* __restrict__ F1p,
    const float* __restrict__ F2p, float* __restrict__ qz,
    u16* __restrict__ qzh, u16* __restrict__ qzl, const float* __restrict__ gw,
    const int* __restrict__ mask, float* __restrict__ out, int final_) {
  int blk = blockIdx.x;
  int ic = blk & 15, b = blk >> 4;
  int i0 = ic * 32;
  int t = threadIdx.x;
  __shared__ float gw_s[64][65];
  __shared__ float qz_s[32][64];
  __shared__ float fg_s[32][65];
  for (int p = t; p < 4096; p += 256) gw_s[p >> 6][p & 63] = gw[p];
  for (int p = t; p < 2048; p += 256) {
    int il = p >> 6, a = p & 63;
    qz_s[il][a] = qz[(b * LL + i0 + il) * 64 + a];
  }
  __syncthreads();
  int gcol = t & 63, il0 = t >> 6;
#pragma unroll
  for (int s = 0; s < 8; s++) {
    int il = il0 + 4 * s;
    float acc = 0.f;
    for (int a = 0; a < 64; a++) acc += qz_s[il][a] * gw_s[gcol][a];
    fg_s[il][gcol] = acc;
  }
  __syncthreads();
  {
    int r = t >> 3, k = t & 7;
    float v[8];
#pragma unroll
    for (int u = 0; u < 8; u++) v[u] = fg_s[r][k * 8 + u];
    float m = v[0];
#pragma unroll
    for (int u = 1; u < 8; u++) m = fmaxf(m, v[u]);
    for (int o = 1; o < 8; o <<= 1) m = fmaxf(m, __shfl_xor(m, o));
    float s = 0.f;
#pragma unroll
    for (int u = 0; u < 8; u++) s += __expf(v[u] - m);
    for (int o = 1; o < 8; o <<= 1) s += __shfl_xor(s, o);
    float mi = (mask[b * LL + i0 + r] != 0) ? 1.f : 0.f;
    float inv = mi / s;
#pragma unroll
    for (int u = 0; u < 8; u++) fg_s[r][k * 8 + u] = __expf(v[u] - m) * inv;
  }
  __syncthreads();
  int a = t & 63;
#pragma unroll
  for (int s = 0; s < 8; s++) {
    int il = il0 + 4 * s;
    float acc = 0.f;
    for (int g2 = 0; g2 < 64; g2++) acc += fg_s[il][g2] * gw_s[g2][a];
    size_t idx = (size_t)(b * LL + i0 + il) * 64 + a;
    float fs = x[idx] + acc;
    for (int p = 0; p < NP; p++)
      fs += F1p[(size_t)p * (BB * 512 * 64) + idx] +
            F2p[(size_t)p * (BB * 512 * 64) + idx];
    if (final_) {
      out[idx] = fs;
    } else {
      float m = fs;
      for (int o = 32; o; o >>= 1) m = fmaxf(m, __shfl_xor(m, o));
      float e = __expf(fs - m);
      float ss = e;
      for (int o = 32; o; o >>= 1) ss += __shfl_xor(ss, o);
      float mi = (mask[b * LL + i0 + il] != 0) ? 1.f : 0.f;
      float r = e / ss * mi;
      qz[idx] = r;
      u16 hi, lo;
      split2(r, hi, lo);
      qzh[idx] = hi;
      qzl[idx] = lo;
    }
  }
}

// ---------------------------------------------------------------------------
extern "C" void kernel_launch(void* const* d_in, const int* in_sizes, int n_in,
                              void* d_out, int out_size, void* d_ws,
                              size_t ws_size, hipStream_t stream) {
  const float* x = (const float*)d_in[0];
  const int* mask = (const int*)d_in[1];
  const float* ternary = (const float*)d_in[2];
  const float* gw = (const float*)d_in[3];
  float* out = (float*)d_out;

  char* w = (char*)d_ws;
  float* qz_f = (float*)(w);                           // 1 MB
  u16* qzh = (u16*)(w + (2 << 20));                    // 512 KB
  u16* qzl = (u16*)(w + (2 << 20) + (512 << 10));      // 512 KB
  u16* qzTh = (u16*)(w + (3 << 20));                   // 512 KB
  u16* TBh = (u16*)(w + (4 << 20));                    // 4 x 128 KB
  u16* TBl = (u16*)(w + (4 << 20) + (128 << 10));
  u16* T1ph = (u16*)(w + (4 << 20) + (256 << 10));
  u16* T2ph = (u16*)(w + (4 << 20) + (384 << 10));
  float* sts = (float*)(w + (5 << 20));                // 128 KB
  float* F1p = (float*)(w + (6 << 20));                // 4 MB (NP=4)
  float* F2p = (float*)(w + (14 << 20));               // 4 MB
  u16* t1h = (u16*)(w + (22 << 20));                   // 8 MB
  u16* A1h = (u16*)(w + (30 << 20));                   // 8 MB
  u16* A2h = (u16*)(w + (38 << 20));                   // 8 MB -> 46 MB total

  repack_kernel<<<256, 256, 0, stream>>>(ternary, TBh, TBl, T1ph, T2ph);
  softmax_z_kernel<<<BB * LL, 64, 0, stream>>>(x, mask, qz_f, qzh, qzl);
  for (int iter = 0; iter < NITER; iter++) {
    t1qzT_kernel<<<1088, 256, 0, stream>>>(qzh, qzl, TBh, TBl, t1h, qzTh);
    a1_kernel<<<512, 512, 0, stream>>>(t1h, qzh, qzTh, mask, sts, A1h);
    a2_kernel<<<512, 512, 0, stream>>>(t1h, qzh, qzTh, sts, mask, A2h);
    mm_fz_kernel<<<512, 256, 0, stream>>>(A1h, A2h, T1ph, T2ph, F1p, F2p);
    fzqg_kernel<<<128, 256, 0, stream>>>(x, F1p, F2p, qz_f, qzh, qzl, gw,
                                         mask, out, iter == NITER - 1);
  }
}

// Round 18
// 232.394 us; speedup vs baseline: 1.3871x; 1.0269x over previous
//
#include <hip/hip_runtime.h>
#include <hip/hip_bf16.h>

#define BB 8
#define LL 512
#define CC 8
#define NITER 3
#define NP 4  // split-K parts for mm_fz

typedef __attribute__((ext_vector_type(8))) short bf16x8;
typedef __attribute__((ext_vector_type(4))) float f32x4;
typedef unsigned short u16;

#define MFMA(A, B, C) __builtin_amdgcn_mfma_f32_16x16x32_bf16(A, B, C, 0, 0, 0)

__device__ inline u16 f2b(float f) {
  __hip_bfloat16 h = __float2bfloat16(f);
  return *reinterpret_cast<u16*>(&h);
}
__device__ inline float b2f(u16 u) {
  __hip_bfloat16 h;
  *reinterpret_cast<u16*>(&h) = u;
  return __bfloat162float(h);
}
__device__ inline void split2(float v, u16& hi, u16& lo) {
  hi = f2b(v);
  lo = f2b(v - b2f(hi));
}

// Stage a [64][64] bf16 tile (row stride ld) into LDS, XOR-swizzled.
__device__ inline void stageT(u16* lds, const u16* __restrict__ src, int ld,
                              int t, int nthr) {
  for (int ch = t; ch < 512; ch += nthr) {
    int r = ch >> 3, seg = ch & 7;
    int byte = (r * 128 + seg * 16) ^ ((r & 7) << 4);
    *(bf16x8*)((char*)lds + byte) = *(const bf16x8*)(src + r * ld + seg * 8);
  }
}
// mfma_16x16x32 operand fragment from swizzled tile: rows row0..row0+15.
__device__ inline bf16x8 frag64(const u16* lds, int row0, int ks, int lane) {
  int r = row0 + (lane & 15);
  int byte = (r * 128 + ks * 64 + ((lane >> 4) << 4)) ^ ((r & 7) << 4);
  return *(const bf16x8*)((const char*)lds + byte);
}

#define ACC_INIT {{0.f,0.f,0.f,0.f},{0.f,0.f,0.f,0.f},{0.f,0.f,0.f,0.f},{0.f,0.f,0.f,0.f}}

// ---------------------------------------------------------------------------
// repack ternary: TB split pairs (t1 GEMM B-side), T1p/T2p hi-only (mm_fz).
// ---------------------------------------------------------------------------
__global__ __launch_bounds__(256) void repack_kernel(
    const float* __restrict__ T, u16* TBh, u16* TBl, u16* T1h, u16* T2h) {
  int tid = blockIdx.x * 256 + threadIdx.x;  // [2][64][64][8]
  int c = tid & 7, e = (tid >> 3) & 63, a = (tid >> 9) & 63, kk = tid >> 15;
  u16 hi, lo;
  split2(T[tid], hi, lo);
  int iTB = ((kk * 8 + c) * 64 + e) * 64 + a;
  int i1 = a * 1024 + kk * 512 + c * 64 + e;
  int i2 = e * 1024 + kk * 512 + c * 64 + a;
  TBh[iTB] = hi;
  TBl[iTB] = lo;
  T1h[i1] = hi;
  T2h[i2] = hi;
}

// ---------------------------------------------------------------------------
// q_z = softmax(x) * m1 ; fp32 + bf16 copy  (iteration 0 only)
// ---------------------------------------------------------------------------
__global__ __launch_bounds__(64) void softmax_z_kernel(
    const float* __restrict__ in, const int* __restrict__ mask,
    float* __restrict__ qz, u16* __restrict__ qzh) {
  int row = blockIdx.x;
  int t = threadIdx.x;
  float v = in[row * 64 + t];
  float m = v;
  for (int o = 32; o; o >>= 1) m = fmaxf(m, __shfl_xor(m, o));
  float e = __expf(v - m);
  float s = e;
  for (int o = 32; o; o >>= 1) s += __shfl_xor(s, o);
  float mi = (mask[row] != 0) ? 1.f : 0.f;
  float r = e / s * mi;
  qz[row * 64 + t] = r;
  qzh[row * 64 + t] = f2b(r);
}

// ---------------------------------------------------------------------------
// fused: blk<1024 -> t1[kk,b,c][i][e] = sum_a qz[b,i,a]*T[kk,a,e,c] (hi out)
//        blk>=1024 -> qzTh[b][a][i] = qzh[b][i][a]
// ---------------------------------------------------------------------------
__global__ __launch_bounds__(256) void t1qzT_kernel(
    const u16* __restrict__ qzh, const u16* __restrict__ TBh,
    const u16* __restrict__ TBl, u16* __restrict__ t1h,
    u16* __restrict__ qzTh) {
  __shared__ u16 smem[12288];  // 24 KB, aliased by both paths
  int blk = blockIdx.x;
  int t = threadIdx.x;
  if (blk >= 1024) {
    int blk2 = blk - 1024;  // b*8 + it
    int it = blk2 & 7, b = blk2 >> 3;
    u16(*s)[65] = (u16(*)[65])smem;
    for (int p = t; p < 4096; p += 256) {
      int r = p >> 6, a = p & 63;
      s[r][a] = qzh[(b * 512 + it * 64 + r) * 64 + a];
    }
    __syncthreads();
    for (int p = t; p < 4096; p += 256) {
      int a = p >> 6, i = p & 63;
      qzTh[(b * 64 + a) * 512 + it * 64 + i] = s[i][a];
    }
    return;
  }
  int it = blk & 7, c = (blk >> 3) & 7, b = (blk >> 6) & 7, kk = blk >> 9;
  u16* ah_s = smem;
  u16* bh_s = smem + 4096;
  u16* bl_s = smem + 8192;
  int lane = t & 63, w = t >> 6;
  stageT(ah_s, qzh + (b * 512 + it * 64) * 64, 64, t, 256);
  stageT(bh_s, TBh + (kk * 8 + c) * 4096, 64, t, 256);
  stageT(bl_s, TBl + (kk * 8 + c) * 4096, 64, t, 256);
  __syncthreads();
  f32x4 acc[4] = ACC_INIT;
  for (int ks = 0; ks < 2; ks++) {
    bf16x8 ah = frag64(ah_s, w * 16, ks, lane);
#pragma unroll
    for (int nt = 0; nt < 4; nt++) {
      acc[nt] = MFMA(ah, frag64(bh_s, nt * 16, ks, lane), acc[nt]);
      acc[nt] = MFMA(ah, frag64(bl_s, nt * 16, ks, lane), acc[nt]);
    }
  }
  size_t base = ((size_t)((kk * 8 + b) * 8 + c)) * 32768;
  int rb = (lane >> 4) * 4, cl = lane & 15;
#pragma unroll
  for (int nt = 0; nt < 4; nt++)
#pragma unroll
    for (int r = 0; r < 4; r++) {
      size_t o = base + (size_t)(it * 64 + w * 16 + rb + r) * 64 + nt * 16 + cl;
      t1h[o] = f2b(acc[nt][r]);
    }
}

// ---------------------------------------------------------------------------
// a1: fused no-max softmax + A1 = (qh*dm) @ qz.  Writes sts (denominators).
// All GEMM operands bf16 (hi-only).  512 threads: wave w -> rows rg=w&3,
// col-half nh=w>>2.
// ---------------------------------------------------------------------------
#define A1_PASS(TFH, ACC, KKis0)                                             \
  {                                                                          \
    f32x4 accq0 = {0.f, 0.f, 0.f, 0.f}, accq1 = {0.f, 0.f, 0.f, 0.f};       \
    _Pragma("unroll") for (int ks = 0; ks < 2; ks++) {                       \
      bf16x8 bh0 = frag64(bx0, (nh * 2) * 16, ks, lane);                     \
      bf16x8 bh1 = frag64(bx0, (nh * 2 + 1) * 16, ks, lane);                 \
      accq0 = MFMA(TFH[ks], bh0, accq0);                                     \
      accq1 = MFMA(TFH[ks], bh1, accq1);                                     \
    }                                                                        \
    _Pragma("unroll") for (int ntl = 0; ntl < 2; ntl++) {                    \
      int col = (nh * 2 + ntl) * 16 + cl;                                    \
      int jg = jt * 64 + col;                                                \
      float mj = (mask[b * 512 + jg] != 0) ? 1.f : 0.f;                      \
      _Pragma("unroll") for (int r = 0; r < 4; r++) {                        \
        int row = rg * 16 + g * 4 + r;                                       \
        int ig = it * 64 + row;                                              \
        float e = __expf(ntl ? accq1[r] : accq0[r]);                         \
        float es, q;                                                         \
        if (KKis0) {                                                         \
          es = (jg > ig) ? e : ((jg == ig) ? 1.f : 0.f);                     \
          q = (jg > ig) ? e * mj : 0.f;                                      \
        } else {                                                             \
          es = (jg < ig) ? e : 0.f;                                          \
          q = (jg < ig) ? e * mj : 0.f;                                      \
        }                                                                    \
        s_run[r] += es;                                                      \
        int byte = (row * 128 + col * 2) ^ ((row & 7) << 4);                 \
        *(u16*)((char*)qh_s + byte) = f2b(q);                                \
      }                                                                      \
    }                                                                        \
    __syncthreads();                                                         \
    _Pragma("unroll") for (int ks = 0; ks < 2; ks++) {                       \
      bf16x8 ah = frag64(qh_s, rg * 16, ks, lane);                           \
      _Pragma("unroll") for (int ntl = 0; ntl < 2; ntl++) {                  \
        int nt = nh * 2 + ntl;                                               \
        bf16x8 bh = frag64(bt0, nt * 16, ks, lane);                          \
        ACC[ntl] = MFMA(ah, bh, ACC[ntl]);                                   \
      }                                                                      \
    }                                                                        \
  }

__global__ __launch_bounds__(512, 4) void a1_kernel(
    const u16* __restrict__ t1h, const u16* __restrict__ qzh,
    const u16* __restrict__ qzTh, const int* __restrict__ mask,
    float* __restrict__ sts, u16* __restrict__ A1h) {
  int blk = blockIdx.x;  // b*64 + c*8 + it
  int it = blk & 7, c = (blk >> 3) & 7, b = blk >> 6;
  __shared__ u16 smem[12544];  // 25088 B
  u16* bx0 = smem;             // qz[jt] hi
  u16* bt0 = smem + 4096;      // qzT hi
  u16* qh_s = smem + 8192;     // qh hi
  float* ps = (float*)(smem + 12288);  // [2][64]
  int t = threadIdx.x, lane = t & 63, w = t >> 6, cl = lane & 15, g = lane >> 4;
  int rg = w & 3, nh = w >> 2;
  const size_t KSTR = (size_t)64 * 32768;
  size_t tb = ((size_t)(b * 8 + c)) * 32768 + it * 4096;
  // prologue: stage both t1 tiles, hoist A-frags
  stageT(bx0, t1h + tb, 64, t, 512);
  stageT(bt0, t1h + tb + KSTR, 64, t, 512);
  __syncthreads();
  bf16x8 tf0h[2], tf1h[2];
#pragma unroll
  for (int ks = 0; ks < 2; ks++) {
    tf0h[ks] = frag64(bx0, rg * 16, ks, lane);
    tf1h[ks] = frag64(bt0, rg * 16, ks, lane);
  }
  float mi_[4], s_run[4];
#pragma unroll
  for (int r = 0; r < 4; r++) {
    mi_[r] = (mask[b * 512 + it * 64 + rg * 16 + g * 4 + r] != 0) ? 1.f : 0.f;
    s_run[r] = 0.f;
  }
  f32x4 accU[2] = {{0.f, 0.f, 0.f, 0.f}, {0.f, 0.f, 0.f, 0.f}};
  f32x4 accL[2] = {{0.f, 0.f, 0.f, 0.f}, {0.f, 0.f, 0.f, 0.f}};

#pragma unroll 1
  for (int jt = 0; jt < 8; jt++) {
    __syncthreads();  // protects hoist reads (jt=0) / prior GEMM reads
    stageT(bx0, qzh + (b * 512 + jt * 64) * 64, 64, t, 512);
    stageT(bt0, qzTh + (size_t)b * 32768 + jt * 64, 512, t, 512);
    __syncthreads();
    if (jt > it) {
      A1_PASS(tf0h, accU, true)
    } else if (jt < it) {
      A1_PASS(tf1h, accL, false)
    } else {
      A1_PASS(tf0h, accU, true)
      __syncthreads();  // qh_s rewrite vs GEMM2 reads
      A1_PASS(tf1h, accL, false)
    }
  }
  // epilogue: one reduction for s, then scale + store
#pragma unroll
  for (int r = 0; r < 4; r++) {
    float s = s_run[r];
    s += __shfl_xor(s, 1);
    s += __shfl_xor(s, 2);
    s += __shfl_xor(s, 4);
    s += __shfl_xor(s, 8);
    s_run[r] = s;
  }
  __syncthreads();
  if (cl == 0) {
#pragma unroll
    for (int r = 0; r < 4; r++) ps[nh * 64 + rg * 16 + g * 4 + r] = s_run[r];
  }
  __syncthreads();
#pragma unroll
  for (int r = 0; r < 4; r++) {
    int row = rg * 16 + g * 4 + r;
    float stot = ps[row] + ps[64 + row];
    float scale = mi_[r] / stot;
    int grow = it * 64 + row;
#pragma unroll
    for (int ntl = 0; ntl < 2; ntl++) {
      size_t o0 = ((size_t)b * 512 + grow) * 1024 + c * 64 +
                  (nh * 2 + ntl) * 16 + cl;
      A1h[o0] = f2b(accU[ntl][r] * scale);
      A1h[o0 + 512] = f2b(accL[ntl][r] * scale);
    }
    if (nh == 0 && cl == 0) sts[(b * 8 + c) * 512 + grow] = stot;
  }
}

// ---------------------------------------------------------------------------
// a2: A2[b][j][kk,c,a] = sum_i qh[kk][i][j]·qz[i][a]  (recompute, uses sts)
// All GEMM operands bf16 (hi-only).
// ---------------------------------------------------------------------------
#define A2_PASS(ACC, KKis0)                                                  \
  {                                                                          \
    f32x4 accq0 = {0.f, 0.f, 0.f, 0.f}, accq1 = {0.f, 0.f, 0.f, 0.f};       \
    _Pragma("unroll") for (int ks = 0; ks < 2; ks++) {                       \
      bf16x8 bh0 = frag64(tsx0, (nh * 2) * 16, ks, lane);                    \
      bf16x8 bh1 = frag64(tsx0, (nh * 2 + 1) * 16, ks, lane);                \
      accq0 = MFMA(afh[ks], bh0, accq0);                                     \
      accq1 = MFMA(afh[ks], bh1, accq1);                                     \
    }                                                                        \
    _Pragma("unroll") for (int ntl = 0; ntl < 2; ntl++) {                    \
      int col = (nh * 2 + ntl) * 16 + cl;                                    \
      int ig = ii * 64 + col;                                                \
      float sim = simi[col];                                                 \
      _Pragma("unroll") for (int r = 0; r < 4; r++) {                        \
        int row = rg * 16 + g * 4 + r;                                       \
        int jg = jt * 64 + row;                                              \
        float e = __expf(ntl ? accq1[r] : accq0[r]);                         \
        bool keep = KKis0 ? (jg > ig) : (jg < ig);                           \
        float q = keep ? e * sim * mjrow[r] : 0.f;                           \
        int byte = (row * 128 + col * 2) ^ ((row & 7) << 4);                 \
        *(u16*)((char*)qh_s + byte) = f2b(q);                                \
      }                                                                      \
    }                                                                        \
    __syncthreads();                                                         \
    _Pragma("unroll") for (int ks = 0; ks < 2; ks++) {                       \
      bf16x8 ah = frag64(qh_s, rg * 16, ks, lane);                           \
      _Pragma("unroll") for (int ntl = 0; ntl < 2; ntl++) {                  \
        int nt = nh * 2 + ntl;                                               \
        bf16x8 bh = frag64(bt0, nt * 16, ks, lane);                          \
        ACC[ntl] = MFMA(ah, bh, ACC[ntl]);                                   \
      }                                                                      \
    }                                                                        \
  }

__global__ __launch_bounds__(512, 4) void a2_kernel(
    const u16* __restrict__ t1h, const u16* __restrict__ qzh,
    const u16* __restrict__ qzTh, const float* __restrict__ sts,
    const int* __restrict__ mask, u16* __restrict__ A2h) {
  int blk = blockIdx.x;  // b*64 + c*8 + jt
  int jt = blk & 7, c = (blk >> 3) & 7, b = blk >> 6;
  __shared__ u16 smem[12416];  // 24832 B
  u16* tsx0 = smem;            // t1 tile hi
  u16* bt0 = smem + 4096;      // qzT hi
  u16* qh_s = smem + 8192;     // qhT hi
  float* simi = (float*)(smem + 12288);  // [64] = mi/s per i
  int t = threadIdx.x, lane = t & 63, w = t >> 6, cl = lane & 15, g = lane >> 4;
  int rg = w & 3, nh = w >> 2;
  const size_t KSTR = (size_t)64 * 32768;
  size_t tbb = ((size_t)(b * 8 + c)) * 32768;
  // prologue: stage qz[jt] hi, hoist A-frags
  stageT(tsx0, qzh + (b * 512 + jt * 64) * 64, 64, t, 512);
  __syncthreads();
  bf16x8 afh[2];
#pragma unroll
  for (int ks = 0; ks < 2; ks++) afh[ks] = frag64(tsx0, rg * 16, ks, lane);
  float mjrow[4];
#pragma unroll
  for (int r = 0; r < 4; r++) {
    int jg = jt * 64 + rg * 16 + g * 4 + r;
    mjrow[r] = (mask[b * 512 + jg] != 0) ? 1.f : 0.f;
  }
  f32x4 accU[2] = {{0.f, 0.f, 0.f, 0.f}, {0.f, 0.f, 0.f, 0.f}};
  f32x4 accL[2] = {{0.f, 0.f, 0.f, 0.f}, {0.f, 0.f, 0.f, 0.f}};

#pragma unroll 1
  for (int ii = 0; ii < 8; ii++) {
    int diag = (ii == jt);
    int kk0 = (ii < jt) ? 0 : 1;
    __syncthreads();
    {
      size_t tsrc = tbb + ii * 4096 + ((diag || kk0 == 0) ? 0 : KSTR);
      stageT(tsx0, t1h + tsrc, 64, t, 512);
    }
    stageT(bt0, qzTh + (size_t)b * 32768 + ii * 64, 512, t, 512);
    if (t < 64) {
      int ig = ii * 64 + t;
      float mi = (mask[b * 512 + ig] != 0) ? 1.f : 0.f;
      simi[t] = mi / sts[(b * 8 + c) * 512 + ig];
    }
    __syncthreads();
    if (diag) {
      A2_PASS(accU, true)
      __syncthreads();
      stageT(tsx0, t1h + tbb + ii * 4096 + KSTR, 64, t, 512);
      __syncthreads();
      A2_PASS(accL, false)
    } else if (kk0 == 0) {
      A2_PASS(accU, true)
    } else {
      A2_PASS(accL, false)
    }
  }
#pragma unroll
  for (int r = 0; r < 4; r++) {
    int row = jt * 64 + rg * 16 + g * 4 + r;
#pragma unroll
    for (int ntl = 0; ntl < 2; ntl++) {
      size_t o0 = ((size_t)b * 512 + row) * 1024 + c * 64 +
                  (nh * 2 + ntl) * 16 + cl;
      A2h[o0] = f2b(accU[ntl][r]);
      A2h[o0 + 512] = f2b(accL[ntl][r]);
    }
  }
}

// ---------------------------------------------------------------------------
// F{1,2} partials: Fp[part][b][m][n] = sum_{K part} A[b][m][K]·Tp[n][K]
// Plain bf16 GEMM.  blk = sel*256 + part*64 + b*8 + it  (sel: 0->F1, 1->F2)
// ---------------------------------------------------------------------------
__global__ __launch_bounds__(256) void mm_fz_kernel(
    const u16* __restrict__ A1h, const u16* __restrict__ A2h,
    const u16* __restrict__ T1ph, const u16* __restrict__ T2ph,
    float* __restrict__ F1p, float* __restrict__ F2p) {
  int blk = blockIdx.x;
  int it = blk & 7, b = (blk >> 3) & 7, part = (blk >> 6) & 3, sel = blk >> 8;
  const u16* Ah = sel ? A2h : A1h;
  const u16* Bh = sel ? T2ph : T1ph;
  float* Fp = (sel ? F2p : F1p) + (size_t)part * (BB * 512 * 64);
  __shared__ u16 ah_s[4096], bh_s[4096];
  int t = threadIdx.x, lane = t & 63, w = t >> 6;
  f32x4 acc[4] = ACC_INIT;
  size_t abase = ((size_t)b * 512 + it * 64) * 1024;
  for (int cc2 = 0; cc2 < 4; cc2++) {
    int ch = part * 4 + cc2;
    __syncthreads();
    stageT(ah_s, Ah + abase + ch * 64, 1024, t, 256);
    stageT(bh_s, Bh + ch * 64, 1024, t, 256);
    __syncthreads();
    for (int ks = 0; ks < 2; ks++) {
      bf16x8 ah = frag64(ah_s, w * 16, ks, lane);
#pragma unroll
      for (int nt = 0; nt < 4; nt++)
        acc[nt] = MFMA(ah, frag64(bh_s, nt * 16, ks, lane), acc[nt]);
    }
  }
  int rb = (lane >> 4) * 4, cl = lane & 15;
#pragma unroll
  for (int nt = 0; nt < 4; nt++)
#pragma unroll
    for (int r = 0; r < 4; r++)
      Fp[((size_t)b * 512 + it * 64 + w * 16 + rb + r) * 64 + nt * 16 + cl] =
          acc[nt][r];
}

// ---------------------------------------------------------------------------
// fused q_g + F_Z (+ Z-softmax for non-final iters)
// ---------------------------------------------------------------------------
__global__ __launch_bounds__(256) void fzqg_kernel(
    const float* __restrict__ x, const float* __restrict__ F1p,
    const float* __restrict__ F2p, float* __restrict__ qz,
    u16* __restrict__ qzh, const float* __restrict__ gw,
    const int* __restrict__ mask, float* __restrict__ out, int final_) {
  int blk = blockIdx.x;
  int ic = blk & 15, b = blk >> 4;
  int i0 = ic * 32;
  int t = threadIdx.x;
  __shared__ float gw_s[64][65];
  __shared__ float qz_s[32][64];
  __shared__ float fg_s[32][65];
  for (int p = t; p < 4096; p += 256) gw_s[p >> 6][p & 63] = gw[p];
  for (int p = t; p < 2048; p += 256) {
    int il = p >> 6, a = p & 63;
    qz_s[il][a] = qz[(b * LL + i0 + il) * 64 + a];
  }
  __syncthreads();
  int gcol = t & 63, il0 = t >> 6;
#pragma unroll
  for (int s = 0; s < 8; s++) {
    int il = il0 + 4 * s;
    float acc = 0.f;
    for (int a = 0; a < 64; a++) acc += qz_s[il][a] * gw_s[gcol][a];
    fg_s[il][gcol] = acc;
  }
  __syncthreads();
  {
    int r = t >> 3, k = t & 7;
    float v[8];
#pragma unroll
    for (int u = 0; u < 8; u++) v[u] = fg_s[r][k * 8 + u];
    float m = v[0];
#pragma unroll
    for (int u = 1; u < 8; u++) m = fmaxf(m, v[u]);
    for (int o = 1; o < 8; o <<= 1) m = fmaxf(m, __shfl_xor(m, o));
    float s = 0.f;
#pragma unroll
    for (int u = 0; u < 8; u++) s += __expf(v[u] - m);
    for (int o = 1; o < 8; o <<= 1) s += __shfl_xor(s, o);
    float mi = (mask[b * LL + i0 + r] != 0) ? 1.f : 0.f;
    float inv = mi / s;
#pragma unroll
    for (int u = 0; u < 8; u++) fg_s[r][k * 8 + u] = __expf(v[u] - m) * inv;
  }
  __syncthreads();
  int a = t & 63;
#pragma unroll
  for (int s = 0; s < 8; s++) {
    int il = il0 + 4 * s;
    float acc = 0.f;
    for (int g2 = 0; g2 < 64; g2++) acc += fg_s[il][g2] * gw_s[g2][a];
    size_t idx = (size_t)(b * LL + i0 + il) * 64 + a;
    float fs = x[idx] + acc;
    for (int p = 0; p < NP; p++)
      fs += F1p[(size_t)p * (BB * 512 * 64) + idx] +
            F2p[(size_t)p * (BB * 512 * 64) + idx];
    if (final_) {
      out[idx] = fs;
    } else {
      float m = fs;
      for (int o = 32; o; o >>= 1) m = fmaxf(m, __shfl_xor(m, o));
      float e = __expf(fs - m);
      float ss = e;
      for (int o = 32; o; o >>= 1) ss += __shfl_xor(ss, o);
      float mi = (mask[b * LL + i0 + il] != 0) ? 1.f : 0.f;
      float r = e / ss * mi;
      qz[idx] = r;
      qzh[idx] = f2b(r);
    }
  }
}

// ---------------------------------------------------------------------------
extern "C" void kernel_launch(void* const* d_in, const int* in_sizes, int n_in,
                              void* d_out, int out_size, void* d_ws,
                              size_t ws_size, hipStream_t stream) {
  const float* x = (const float*)d_in[0];
  const int* mask = (const int*)d_in[1];
  const float* ternary = (const float*)d_in[2];
  const float* gw = (const float*)d_in[3];
  float* out = (float*)d_out;

  char* w = (char*)d_ws;
  float* qz_f = (float*)(w);                           // 1 MB
  u16* qzh = (u16*)(w + (2 << 20));                    // 512 KB
  u16* qzTh = (u16*)(w + (3 << 20));                   // 512 KB
  u16* TBh = (u16*)(w + (4 << 20));                    // 4 x 128 KB
  u16* TBl = (u16*)(w + (4 << 20) + (128 << 10));
  u16* T1ph = (u16*)(w + (4 << 20) + (256 << 10));
  u16* T2ph = (u16*)(w + (4 << 20) + (384 << 10));
  float* sts = (float*)(w + (5 << 20));                // 128 KB
  float* F1p = (float*)(w + (6 << 20));                // 4 MB (NP=4)
  float* F2p = (float*)(w + (14 << 20));               // 4 MB
  u16* t1h = (u16*)(w + (22 << 20));                   // 8 MB
  u16* A1h = (u16*)(w + (30 << 20));                   // 8 MB
  u16* A2h = (u16*)(w + (38 << 20));                   // 8 MB -> 46 MB total

  repack_kernel<<<256, 256, 0, stream>>>(ternary, TBh, TBl, T1ph, T2ph);
  softmax_z_kernel<<<BB * LL, 64, 0, stream>>>(x, mask, qz_f, qzh);
  for (int iter = 0; iter < NITER; iter++) {
    t1qzT_kernel<<<1088, 256, 0, stream>>>(qzh, TBh, TBl, t1h, qzTh);
    a1_kernel<<<512, 512, 0, stream>>>(t1h, qzh, qzTh, mask, sts, A1h);
    a2_kernel<<<512, 512, 0, stream>>>(t1h, qzh, qzTh, sts, mask, A2h);
    mm_fz_kernel<<<512, 256, 0, stream>>>(A1h, A2h, T1ph, T2ph, F1p, F2p);
    fzqg_kernel<<<128, 256, 0, stream>>>(x, F1p, F2p, qz_f, qzh, gw, mask,
                                         out, iter == NITER - 1);
  }
}